// Round 1
// baseline (1246.974 us; speedup 1.0000x reference)
//
#include <hip/hip_runtime.h>

#define N_NODES 50000
#define N_EDGES 800000
#define BN_EPS 1e-5f

// ---------------- CSR build ----------------

__global__ void hist_kernel(const int* __restrict__ dst, int* __restrict__ deg, int e) {
    int i = blockIdx.x * blockDim.x + threadIdx.x;
    int stride = gridDim.x * blockDim.x;
    for (; i < e; i += stride) atomicAdd(&deg[dst[i]], 1);
}

__global__ void exscan_kernel(const int* __restrict__ deg, int* __restrict__ rowptr, int n) {
    __shared__ int sdata[256];
    __shared__ int carry_s;
    int tid = threadIdx.x;
    if (tid == 0) carry_s = 0;
    __syncthreads();
    for (int base = 0; base < n; base += 256) {
        int i = base + tid;
        int v = (i < n) ? deg[i] : 0;
        sdata[tid] = v;
        __syncthreads();
#pragma unroll
        for (int off = 1; off < 256; off <<= 1) {
            int t = (tid >= off) ? sdata[tid - off] : 0;
            __syncthreads();
            sdata[tid] += t;
            __syncthreads();
        }
        int incl = sdata[tid];
        int total = sdata[255];
        int c = carry_s;
        if (i < n) rowptr[i] = c + incl - v;
        __syncthreads();
        if (tid == 0) carry_s = c + total;
        __syncthreads();
    }
    if (tid == 0) rowptr[n] = carry_s;
}

__global__ void copy_int_kernel(const int* __restrict__ a, int* __restrict__ b, int n) {
    int i = blockIdx.x * blockDim.x + threadIdx.x;
    if (i < n) b[i] = a[i];
}

__global__ void scatter_kernel(const int* __restrict__ src, const int* __restrict__ dst,
                               int* __restrict__ wptr, int* __restrict__ col, int e) {
    int i = blockIdx.x * blockDim.x + threadIdx.x;
    int stride = gridDim.x * blockDim.x;
    for (; i < e; i += stride) {
        int d = dst[i];
        int p = atomicAdd(&wptr[d], 1);
        col[p] = src[i];
    }
}

// ---------------- aggregation: z[i] = h[i] + sum_{j in N(i)} h[j] ----------------
// LPN lanes per node, each lane owns one float4 of the feature row (dim = 4*LPN).

template <int LPN>
__global__ __launch_bounds__(256) void aggregate_kernel(const float* __restrict__ h,
                                                        const int* __restrict__ rowptr,
                                                        const int* __restrict__ col,
                                                        float* __restrict__ z, int n) {
    const int gpb = 256 / LPN;
    int gid = threadIdx.x / LPN;
    int l = threadIdx.x % LPN;
    int node = blockIdx.x * gpb + gid;
    if (node >= n) return;
    const float4* hv = (const float4*)h;
    float4 acc = hv[(size_t)node * LPN + l];  // self term
    int s = rowptr[node], epos = rowptr[node + 1];
    for (int e = s; e < epos; ++e) {
        int j = col[e];
        float4 v = hv[(size_t)j * LPN + l];
        acc.x += v.x; acc.y += v.y; acc.z += v.z; acc.w += v.w;
    }
    ((float4*)z)[(size_t)node * LPN + l] = acc;
}

// ---------------- fp32 tiled GEMM: C = epilogue(A @ W + bias) ----------------
// A: M x K row-major, W: K x Nn row-major. BM=BN=64, BK=16, 256 thr, 4x4/thread.
// bn==0: relu(acc + b);  bn==1: relu((acc + b - mu)*g*rsqrt(var+eps) + beta)

__global__ __launch_bounds__(256) void gemm_kernel(
    const float* __restrict__ A, const float* __restrict__ W,
    const float* __restrict__ bias, float* __restrict__ C,
    int M, int K, int Nn, int bn,
    const float* __restrict__ g, const float* __restrict__ be,
    const float* __restrict__ mu, const float* __restrict__ var) {
    __shared__ float As[16][64];
    __shared__ float Ws[16][64];
    const int tid = threadIdx.x;
    const int row0 = blockIdx.x * 64;
    const int col0 = blockIdx.y * 64;
    const int am = tid >> 2;            // 0..63
    const int ak = (tid & 3) << 2;      // 0,4,8,12
    const int wk = tid >> 4;            // 0..15
    const int wn = (tid & 15) << 2;     // 0..60
    const int tm = (tid >> 4) << 2;
    const int tn = (tid & 15) << 2;
    float acc[4][4] = {};
    const int arow = row0 + am;
    for (int k0 = 0; k0 < K; k0 += 16) {
        float4 av = make_float4(0.f, 0.f, 0.f, 0.f);
        if (arow < M) av = *(const float4*)(A + (size_t)arow * K + k0 + ak);
        As[ak + 0][am] = av.x;
        As[ak + 1][am] = av.y;
        As[ak + 2][am] = av.z;
        As[ak + 3][am] = av.w;
        *(float4*)(&Ws[wk][wn]) = *(const float4*)(W + (size_t)(k0 + wk) * Nn + col0 + wn);
        __syncthreads();
#pragma unroll
        for (int kk = 0; kk < 16; ++kk) {
            float4 a = *(const float4*)(&As[kk][tm]);
            float4 w = *(const float4*)(&Ws[kk][tn]);
            acc[0][0] += a.x * w.x; acc[0][1] += a.x * w.y; acc[0][2] += a.x * w.z; acc[0][3] += a.x * w.w;
            acc[1][0] += a.y * w.x; acc[1][1] += a.y * w.y; acc[1][2] += a.y * w.z; acc[1][3] += a.y * w.w;
            acc[2][0] += a.z * w.x; acc[2][1] += a.z * w.y; acc[2][2] += a.z * w.z; acc[2][3] += a.z * w.w;
            acc[3][0] += a.w * w.x; acc[3][1] += a.w * w.y; acc[3][2] += a.w * w.z; acc[3][3] += a.w * w.w;
        }
        __syncthreads();
    }
    float sc[4], sh[4];
#pragma unroll
    for (int j = 0; j < 4; ++j) {
        int c = col0 + tn + j;
        float b = bias[c];
        if (bn) {
            float s = g[c] * rsqrtf(var[c] + BN_EPS);
            sc[j] = s;
            sh[j] = be[c] - mu[c] * s + b * s;
        } else {
            sc[j] = 1.f;
            sh[j] = b;
        }
    }
#pragma unroll
    for (int i = 0; i < 4; ++i) {
        int r = row0 + tm + i;
        if (r < M) {
            float4 o;
            o.x = fmaxf(acc[i][0] * sc[0] + sh[0], 0.f);
            o.y = fmaxf(acc[i][1] * sc[1] + sh[1], 0.f);
            o.z = fmaxf(acc[i][2] * sc[2] + sh[2], 0.f);
            o.w = fmaxf(acc[i][3] * sc[3] + sh[3], 0.f);
            *(float4*)(C + (size_t)r * Nn + col0 + tn) = o;
        }
    }
}

// ---------------- classifier: out = h @ wc + bc, K=64, Nout=2 ----------------

__global__ __launch_bounds__(256) void classifier_kernel(
    const float* __restrict__ h, const float* __restrict__ wc,
    const float* __restrict__ bc, float* __restrict__ out, int n) {
    int wave = threadIdx.x >> 6;
    int lane = threadIdx.x & 63;
    int row = blockIdx.x * 4 + wave;
    if (row >= n) return;
    float v = h[(size_t)row * 64 + lane];
    float s0 = v * wc[lane * 2 + 0];
    float s1 = v * wc[lane * 2 + 1];
#pragma unroll
    for (int off = 32; off > 0; off >>= 1) {
        s0 += __shfl_down(s0, off, 64);
        s1 += __shfl_down(s1, off, 64);
    }
    if (lane == 0) {
        out[(size_t)row * 2 + 0] = s0 + bc[0];
        out[(size_t)row * 2 + 1] = s1 + bc[1];
    }
}

// ---------------- launch ----------------

extern "C" void kernel_launch(void* const* d_in, const int* in_sizes, int n_in,
                              void* d_out, int out_size, void* d_ws, size_t ws_size,
                              hipStream_t stream) {
    const float* x = (const float*)d_in[0];
    const int* ei = (const int*)d_in[1];
    const int* src = ei;             // edge_index[0]
    const int* dst = ei + N_EDGES;   // edge_index[1]
    const float* w[4][2];
    const float* b[4][2];
    const float* bng[4];
    const float* bnb[4];
    const float* bnm[4];
    const float* bnv[4];
    int idx = 2;
    for (int i = 0; i < 4; ++i) {
        w[i][0] = (const float*)d_in[idx++];
        b[i][0] = (const float*)d_in[idx++];
        w[i][1] = (const float*)d_in[idx++];
        b[i][1] = (const float*)d_in[idx++];
        bng[i] = (const float*)d_in[idx++];
        bnb[i] = (const float*)d_in[idx++];
        bnm[i] = (const float*)d_in[idx++];
        bnv[i] = (const float*)d_in[idx++];
    }
    const float* wc = (const float*)d_in[idx++];
    const float* bc = (const float*)d_in[idx++];
    float* out = (float*)d_out;

    char* ws = (char*)d_ws;
    size_t off = 0;
    auto alloc = [&](size_t bytes) {
        char* p = ws + off;
        off = (off + bytes + 255) & ~(size_t)255;
        return p;
    };
    int* deg = (int*)alloc((size_t)N_NODES * 4);
    int* rowptr = (int*)alloc((size_t)(N_NODES + 1) * 4);
    int* wptr = (int*)alloc((size_t)N_NODES * 4);
    int* col = (int*)alloc((size_t)N_EDGES * 4);
    float* bufA = (float*)alloc((size_t)N_NODES * 256 * 4);
    float* bufB = (float*)alloc((size_t)N_NODES * 256 * 4);
    float* bufC = (float*)alloc((size_t)N_NODES * 256 * 4);
    (void)ws_size;

    // CSR build (edge_index is identical every call; ws is re-poisoned, so rebuild)
    hipMemsetAsync(deg, 0, (size_t)N_NODES * 4, stream);
    hist_kernel<<<3125, 256, 0, stream>>>(dst, deg, N_EDGES);
    exscan_kernel<<<1, 256, 0, stream>>>(deg, rowptr, N_NODES);
    copy_int_kernel<<<(N_NODES + 255) / 256, 256, 0, stream>>>(rowptr, wptr, N_NODES);
    scatter_kernel<<<3125, 256, 0, stream>>>(src, dst, wptr, col, N_EDGES);

    const int dims_in[4] = {256, 128, 256, 128};
    const int dims_h[4] = {128, 256, 128, 64};
    const float* hin = x;
    for (int L = 0; L < 4; ++L) {
        int din = dims_in[L];
        int dh = dims_h[L];
        if (din == 256)
            aggregate_kernel<64><<<(N_NODES + 3) / 4, 256, 0, stream>>>(hin, rowptr, col, bufA, N_NODES);
        else
            aggregate_kernel<32><<<(N_NODES + 7) / 8, 256, 0, stream>>>(hin, rowptr, col, bufA, N_NODES);
        dim3 g1((N_NODES + 63) / 64, dh / 64);
        gemm_kernel<<<g1, 256, 0, stream>>>(bufA, w[L][0], b[L][0], bufB, N_NODES, din, dh, 0,
                                            nullptr, nullptr, nullptr, nullptr);
        dim3 g2((N_NODES + 63) / 64, dh / 64);
        gemm_kernel<<<g2, 256, 0, stream>>>(bufB, w[L][1], b[L][1], bufC, N_NODES, dh, dh, 1,
                                            bng[L], bnb[L], bnm[L], bnv[L]);
        hin = bufC;
    }
    classifier_kernel<<<(N_NODES + 3) / 4, 256, 0, stream>>>(bufC, wc, bc, out, N_NODES);
}

// Round 2
// 1037.376 us; speedup vs baseline: 1.2020x; 1.2020x over previous
//
#include <hip/hip_runtime.h>

#define N_NODES 50000
#define N_EDGES 800000
#define BN_EPS 1e-5f
#define SCAN_BLOCKS 196  // ceil(50000/256)

// ---------------- CSR build ----------------

__global__ void hist_kernel(const int* __restrict__ dst, int* __restrict__ deg, int e) {
    int i = blockIdx.x * blockDim.x + threadIdx.x;
    int stride = gridDim.x * blockDim.x;
    for (; i < e; i += stride) atomicAdd(&deg[dst[i]], 1);
}

// per-256-thread-block exclusive scan helper: returns exclusive prefix of v,
// writes block total to *total (all threads).
__device__ inline int block_exscan256(int v, int tid, int* total) {
    int lane = tid & 63;
    int wave = tid >> 6;
    int incl = v;
#pragma unroll
    for (int off = 1; off < 64; off <<= 1) {
        int t = __shfl_up(incl, off, 64);
        if (lane >= off) incl += t;
    }
    __shared__ int wsum[4];
    if (lane == 63) wsum[wave] = incl;
    __syncthreads();
    int w0 = wsum[0], w1 = wsum[1], w2 = wsum[2], w3 = wsum[3];
    __syncthreads();
    int wofs = (wave > 0 ? w0 : 0) + (wave > 1 ? w1 : 0) + (wave > 2 ? w2 : 0);
    *total = w0 + w1 + w2 + w3;
    return wofs + incl - v;
}

// stage 1: per-block sums of deg
__global__ __launch_bounds__(256) void scan_reduce_kernel(const int* __restrict__ deg,
                                                          int* __restrict__ bsum, int n) {
    int tid = threadIdx.x;
    int i = blockIdx.x * 256 + tid;
    int v = (i < n) ? deg[i] : 0;
    int lane = tid & 63;
    int wave = tid >> 6;
#pragma unroll
    for (int off = 32; off > 0; off >>= 1) v += __shfl_down(v, off, 64);
    __shared__ int wsum[4];
    if (lane == 0) wsum[wave] = v;
    __syncthreads();
    if (tid == 0) bsum[blockIdx.x] = wsum[0] + wsum[1] + wsum[2] + wsum[3];
}

// stage 2: exclusive scan of block sums (B <= 256), one block; writes rowptr[n]=total
__global__ __launch_bounds__(256) void scan_bsum_kernel(int* __restrict__ bsum, int B,
                                                        int* __restrict__ rowptr, int n) {
    int tid = threadIdx.x;
    int v = (tid < B) ? bsum[tid] : 0;
    int total;
    int excl = block_exscan256(v, tid, &total);
    if (tid < B) bsum[tid] = excl;
    if (tid == 0) rowptr[n] = total;
}

// stage 3: per-block exclusive scan + block offset; writes rowptr and wptr
__global__ __launch_bounds__(256) void scan_apply_kernel(const int* __restrict__ deg,
                                                         const int* __restrict__ bsum,
                                                         int* __restrict__ rowptr,
                                                         int* __restrict__ wptr, int n) {
    int tid = threadIdx.x;
    int i = blockIdx.x * 256 + tid;
    int v = (i < n) ? deg[i] : 0;
    int total;
    int excl = block_exscan256(v, tid, &total);
    if (i < n) {
        int r = bsum[blockIdx.x] + excl;
        rowptr[i] = r;
        wptr[i] = r;
    }
}

__global__ void scatter_kernel(const int* __restrict__ src, const int* __restrict__ dst,
                               int* __restrict__ wptr, int* __restrict__ col, int e) {
    int i = blockIdx.x * blockDim.x + threadIdx.x;
    int stride = gridDim.x * blockDim.x;
    for (; i < e; i += stride) {
        int d = dst[i];
        int p = atomicAdd(&wptr[d], 1);
        col[p] = src[i];
    }
}

// ---------------- aggregation: z[i] = h[i] + sum_{j in N(i)} h[j] ----------------

template <int LPN>
__global__ __launch_bounds__(256) void aggregate_kernel(const float* __restrict__ h,
                                                        const int* __restrict__ rowptr,
                                                        const int* __restrict__ col,
                                                        float* __restrict__ z, int n) {
    const int gpb = 256 / LPN;
    int gid = threadIdx.x / LPN;
    int l = threadIdx.x % LPN;
    int node = blockIdx.x * gpb + gid;
    if (node >= n) return;
    const float4* hv = (const float4*)h;
    float4 acc = hv[(size_t)node * LPN + l];  // self term
    int s = rowptr[node], epos = rowptr[node + 1];
    for (int e = s; e < epos; ++e) {
        int j = col[e];
        float4 v = hv[(size_t)j * LPN + l];
        acc.x += v.x; acc.y += v.y; acc.z += v.z; acc.w += v.w;
    }
    ((float4*)z)[(size_t)node * LPN + l] = acc;
}

// ---------------- fp32 tiled GEMM: C = epilogue(A @ W + bias) ----------------
// A: M x K row-major, W: K x Nn row-major. BM=BN=64, BK=16, 256 thr, 4x4/thread.
// bn==0: relu(acc + b);  bn==1: relu((acc + b - mu)*g*rsqrt(var+eps) + beta)

__global__ __launch_bounds__(256) void gemm_kernel(
    const float* __restrict__ A, const float* __restrict__ W,
    const float* __restrict__ bias, float* __restrict__ C,
    int M, int K, int Nn, int bn,
    const float* __restrict__ g, const float* __restrict__ be,
    const float* __restrict__ mu, const float* __restrict__ var) {
    __shared__ float As[16][64];
    __shared__ float Ws[16][64];
    const int tid = threadIdx.x;
    const int row0 = blockIdx.x * 64;
    const int col0 = blockIdx.y * 64;
    const int am = tid >> 2;            // 0..63
    const int ak = (tid & 3) << 2;      // 0,4,8,12
    const int wk = tid >> 4;            // 0..15
    const int wn = (tid & 15) << 2;     // 0..60
    const int tm = (tid >> 4) << 2;
    const int tn = (tid & 15) << 2;
    float acc[4][4] = {};
    const int arow = row0 + am;
    for (int k0 = 0; k0 < K; k0 += 16) {
        float4 av = make_float4(0.f, 0.f, 0.f, 0.f);
        if (arow < M) av = *(const float4*)(A + (size_t)arow * K + k0 + ak);
        As[ak + 0][am] = av.x;
        As[ak + 1][am] = av.y;
        As[ak + 2][am] = av.z;
        As[ak + 3][am] = av.w;
        *(float4*)(&Ws[wk][wn]) = *(const float4*)(W + (size_t)(k0 + wk) * Nn + col0 + wn);
        __syncthreads();
#pragma unroll
        for (int kk = 0; kk < 16; ++kk) {
            float4 a = *(const float4*)(&As[kk][tm]);
            float4 w = *(const float4*)(&Ws[kk][tn]);
            acc[0][0] += a.x * w.x; acc[0][1] += a.x * w.y; acc[0][2] += a.x * w.z; acc[0][3] += a.x * w.w;
            acc[1][0] += a.y * w.x; acc[1][1] += a.y * w.y; acc[1][2] += a.y * w.z; acc[1][3] += a.y * w.w;
            acc[2][0] += a.z * w.x; acc[2][1] += a.z * w.y; acc[2][2] += a.z * w.z; acc[2][3] += a.z * w.w;
            acc[3][0] += a.w * w.x; acc[3][1] += a.w * w.y; acc[3][2] += a.w * w.z; acc[3][3] += a.w * w.w;
        }
        __syncthreads();
    }
    float sc[4], sh[4];
#pragma unroll
    for (int j = 0; j < 4; ++j) {
        int c = col0 + tn + j;
        float b = bias[c];
        if (bn) {
            float s = g[c] * rsqrtf(var[c] + BN_EPS);
            sc[j] = s;
            sh[j] = be[c] - mu[c] * s + b * s;
        } else {
            sc[j] = 1.f;
            sh[j] = b;
        }
    }
#pragma unroll
    for (int i = 0; i < 4; ++i) {
        int r = row0 + tm + i;
        if (r < M) {
            float4 o;
            o.x = fmaxf(acc[i][0] * sc[0] + sh[0], 0.f);
            o.y = fmaxf(acc[i][1] * sc[1] + sh[1], 0.f);
            o.z = fmaxf(acc[i][2] * sc[2] + sh[2], 0.f);
            o.w = fmaxf(acc[i][3] * sc[3] + sh[3], 0.f);
            *(float4*)(C + (size_t)r * Nn + col0 + tn) = o;
        }
    }
}

// ---------------- classifier: out = h @ wc + bc, K=64, Nout=2 ----------------

__global__ __launch_bounds__(256) void classifier_kernel(
    const float* __restrict__ h, const float* __restrict__ wc,
    const float* __restrict__ bc, float* __restrict__ out, int n) {
    int wave = threadIdx.x >> 6;
    int lane = threadIdx.x & 63;
    int row = blockIdx.x * 4 + wave;
    if (row >= n) return;
    float v = h[(size_t)row * 64 + lane];
    float s0 = v * wc[lane * 2 + 0];
    float s1 = v * wc[lane * 2 + 1];
#pragma unroll
    for (int off = 32; off > 0; off >>= 1) {
        s0 += __shfl_down(s0, off, 64);
        s1 += __shfl_down(s1, off, 64);
    }
    if (lane == 0) {
        out[(size_t)row * 2 + 0] = s0 + bc[0];
        out[(size_t)row * 2 + 1] = s1 + bc[1];
    }
}

// ---------------- launch ----------------

extern "C" void kernel_launch(void* const* d_in, const int* in_sizes, int n_in,
                              void* d_out, int out_size, void* d_ws, size_t ws_size,
                              hipStream_t stream) {
    const float* x = (const float*)d_in[0];
    const int* ei = (const int*)d_in[1];
    const int* src = ei;             // edge_index[0]
    const int* dst = ei + N_EDGES;   // edge_index[1]
    const float* w[4][2];
    const float* b[4][2];
    const float* bng[4];
    const float* bnb[4];
    const float* bnm[4];
    const float* bnv[4];
    int idx = 2;
    for (int i = 0; i < 4; ++i) {
        w[i][0] = (const float*)d_in[idx++];
        b[i][0] = (const float*)d_in[idx++];
        w[i][1] = (const float*)d_in[idx++];
        b[i][1] = (const float*)d_in[idx++];
        bng[i] = (const float*)d_in[idx++];
        bnb[i] = (const float*)d_in[idx++];
        bnm[i] = (const float*)d_in[idx++];
        bnv[i] = (const float*)d_in[idx++];
    }
    const float* wc = (const float*)d_in[idx++];
    const float* bc = (const float*)d_in[idx++];
    float* out = (float*)d_out;

    char* ws = (char*)d_ws;
    size_t off = 0;
    auto alloc = [&](size_t bytes) {
        char* p = ws + off;
        off = (off + bytes + 255) & ~(size_t)255;
        return p;
    };
    int* deg = (int*)alloc((size_t)N_NODES * 4);
    int* rowptr = (int*)alloc((size_t)(N_NODES + 1) * 4);
    int* wptr = (int*)alloc((size_t)N_NODES * 4);
    int* bsum = (int*)alloc((size_t)SCAN_BLOCKS * 4);
    int* col = (int*)alloc((size_t)N_EDGES * 4);
    float* bufA = (float*)alloc((size_t)N_NODES * 256 * 4);
    float* bufB = (float*)alloc((size_t)N_NODES * 256 * 4);
    float* bufC = (float*)alloc((size_t)N_NODES * 256 * 4);
    (void)ws_size;

    // CSR build (hierarchical scan: reduce -> scan block sums -> apply)
    hipMemsetAsync(deg, 0, (size_t)N_NODES * 4, stream);
    hist_kernel<<<3125, 256, 0, stream>>>(dst, deg, N_EDGES);
    scan_reduce_kernel<<<SCAN_BLOCKS, 256, 0, stream>>>(deg, bsum, N_NODES);
    scan_bsum_kernel<<<1, 256, 0, stream>>>(bsum, SCAN_BLOCKS, rowptr, N_NODES);
    scan_apply_kernel<<<SCAN_BLOCKS, 256, 0, stream>>>(deg, bsum, rowptr, wptr, N_NODES);
    scatter_kernel<<<3125, 256, 0, stream>>>(src, dst, wptr, col, N_EDGES);

    const int dims_in[4] = {256, 128, 256, 128};
    const int dims_h[4] = {128, 256, 128, 64};
    const float* hin = x;
    for (int L = 0; L < 4; ++L) {
        int din = dims_in[L];
        int dh = dims_h[L];
        if (din == 256)
            aggregate_kernel<64><<<(N_NODES + 3) / 4, 256, 0, stream>>>(hin, rowptr, col, bufA, N_NODES);
        else
            aggregate_kernel<32><<<(N_NODES + 7) / 8, 256, 0, stream>>>(hin, rowptr, col, bufA, N_NODES);
        dim3 g1((N_NODES + 63) / 64, dh / 64);
        gemm_kernel<<<g1, 256, 0, stream>>>(bufA, w[L][0], b[L][0], bufB, N_NODES, din, dh, 0,
                                            nullptr, nullptr, nullptr, nullptr);
        dim3 g2((N_NODES + 63) / 64, dh / 64);
        gemm_kernel<<<g2, 256, 0, stream>>>(bufB, w[L][1], b[L][1], bufC, N_NODES, dh, dh, 1,
                                            bng[L], bnb[L], bnm[L], bnv[L]);
        hin = bufC;
    }
    classifier_kernel<<<(N_NODES + 3) / 4, 256, 0, stream>>>(bufC, wc, bc, out, N_NODES);
}

// Round 3
// 693.170 us; speedup vs baseline: 1.7989x; 1.4966x over previous
//
#include <hip/hip_runtime.h>

#define N_NODES 50000
#define N_EDGES 800000
#define BN_EPS 1e-5f
#define SCAN_BLOCKS 196  // ceil(50000/256)

typedef __attribute__((ext_vector_type(8))) short bshort8;
typedef __attribute__((ext_vector_type(4))) float f32x4;

__device__ inline float bf2f(unsigned int u16) {
    return __uint_as_float(u16 << 16);
}
__device__ inline unsigned short f2bf(float f) {
    unsigned int u = __float_as_uint(f);
    u = (u + 0x7FFFu + ((u >> 16) & 1u)) >> 16;
    return (unsigned short)u;
}

// ---------------- CSR build ----------------

__global__ void hist_kernel(const int* __restrict__ dst, int* __restrict__ deg, int e) {
    int i = blockIdx.x * blockDim.x + threadIdx.x;
    int stride = gridDim.x * blockDim.x;
    for (; i < e; i += stride) atomicAdd(&deg[dst[i]], 1);
}

__device__ inline int block_exscan256(int v, int tid, int* total) {
    int lane = tid & 63;
    int wave = tid >> 6;
    int incl = v;
#pragma unroll
    for (int off = 1; off < 64; off <<= 1) {
        int t = __shfl_up(incl, off, 64);
        if (lane >= off) incl += t;
    }
    __shared__ int wsum[4];
    if (lane == 63) wsum[wave] = incl;
    __syncthreads();
    int w0 = wsum[0], w1 = wsum[1], w2 = wsum[2], w3 = wsum[3];
    __syncthreads();
    int wofs = (wave > 0 ? w0 : 0) + (wave > 1 ? w1 : 0) + (wave > 2 ? w2 : 0);
    *total = w0 + w1 + w2 + w3;
    return wofs + incl - v;
}

__global__ __launch_bounds__(256) void scan_reduce_kernel(const int* __restrict__ deg,
                                                          int* __restrict__ bsum, int n) {
    int tid = threadIdx.x;
    int i = blockIdx.x * 256 + tid;
    int v = (i < n) ? deg[i] : 0;
    int lane = tid & 63;
    int wave = tid >> 6;
#pragma unroll
    for (int off = 32; off > 0; off >>= 1) v += __shfl_down(v, off, 64);
    __shared__ int wsum[4];
    if (lane == 0) wsum[wave] = v;
    __syncthreads();
    if (tid == 0) bsum[blockIdx.x] = wsum[0] + wsum[1] + wsum[2] + wsum[3];
}

__global__ __launch_bounds__(256) void scan_bsum_kernel(int* __restrict__ bsum, int B,
                                                        int* __restrict__ rowptr, int n) {
    int tid = threadIdx.x;
    int v = (tid < B) ? bsum[tid] : 0;
    int total;
    int excl = block_exscan256(v, tid, &total);
    if (tid < B) bsum[tid] = excl;
    if (tid == 0) rowptr[n] = total;
}

__global__ __launch_bounds__(256) void scan_apply_kernel(const int* __restrict__ deg,
                                                         const int* __restrict__ bsum,
                                                         int* __restrict__ rowptr,
                                                         int* __restrict__ wptr, int n) {
    int tid = threadIdx.x;
    int i = blockIdx.x * 256 + tid;
    int v = (i < n) ? deg[i] : 0;
    int total;
    int excl = block_exscan256(v, tid, &total);
    if (i < n) {
        int r = bsum[blockIdx.x] + excl;
        rowptr[i] = r;
        wptr[i] = r;
    }
}

__global__ void scatter_kernel(const int* __restrict__ src, const int* __restrict__ dst,
                               int* __restrict__ wptr, int* __restrict__ col, int e) {
    int i = blockIdx.x * blockDim.x + threadIdx.x;
    int stride = gridDim.x * blockDim.x;
    for (; i < e; i += stride) {
        int d = dst[i];
        int p = atomicAdd(&wptr[d], 1);
        col[p] = src[i];
    }
}

// ---------------- conversions ----------------

__global__ __launch_bounds__(256) void f2bf_kernel(const float* __restrict__ src,
                                                   unsigned short* __restrict__ dst, int n) {
    int i = (blockIdx.x * 256 + threadIdx.x) * 4;
    if (i >= n) return;
    float4 v = *(const float4*)(src + i);
    ushort4 o;
    o.x = f2bf(v.x); o.y = f2bf(v.y); o.z = f2bf(v.z); o.w = f2bf(v.w);
    *(ushort4*)(dst + i) = o;
}

struct WT8 {
    const float* src[8];
    unsigned short* dst[8];
    int K[8];
    int N[8];
};

// W[K][N] fp32 -> Wt[N][K] bf16 (N,K are powers of two)
__global__ __launch_bounds__(256) void wtconv_kernel(WT8 p) {
    int wi = blockIdx.y;
    int K = p.K[wi], N = p.N[wi];
    int idx = blockIdx.x * 256 + threadIdx.x;
    if (idx >= K * N) return;
    int logn = 31 - __clz(N);
    int n = idx & (N - 1);
    int k = idx >> logn;
    p.dst[wi][(size_t)n * K + k] = f2bf(p.src[wi][idx]);
}

// ---------------- aggregation (bf16): z[i] = h[i] + sum_{j in N(i)} h[j] ----------------
// LPN lanes per node, each lane owns 8 bf16 feats (one uint4).

__device__ inline void acc8(uint4 v, float* a) {
    a[0] += bf2f(v.x & 0xFFFFu); a[1] += __uint_as_float(v.x & 0xFFFF0000u);
    a[2] += bf2f(v.y & 0xFFFFu); a[3] += __uint_as_float(v.y & 0xFFFF0000u);
    a[4] += bf2f(v.z & 0xFFFFu); a[5] += __uint_as_float(v.z & 0xFFFF0000u);
    a[6] += bf2f(v.w & 0xFFFFu); a[7] += __uint_as_float(v.w & 0xFFFF0000u);
}

template <int LPN>
__global__ __launch_bounds__(256) void aggregate_bf16_kernel(
    const unsigned short* __restrict__ h, const int* __restrict__ rowptr,
    const int* __restrict__ col, unsigned short* __restrict__ z, int n) {
    const int gpb = 256 / LPN;
    int gid = threadIdx.x / LPN;
    int l = threadIdx.x % LPN;
    int node = blockIdx.x * gpb + gid;
    if (node >= n) return;
    const uint4* hv = (const uint4*)h;
    float a[8] = {};
    acc8(hv[(size_t)node * LPN + l], a);  // self
    int s = rowptr[node], epos = rowptr[node + 1];
    for (int e = s; e < epos; ++e) {
        int j = col[e];
        acc8(hv[(size_t)j * LPN + l], a);
    }
    uint4 o;
    o.x = (unsigned int)f2bf(a[0]) | ((unsigned int)f2bf(a[1]) << 16);
    o.y = (unsigned int)f2bf(a[2]) | ((unsigned int)f2bf(a[3]) << 16);
    o.z = (unsigned int)f2bf(a[4]) | ((unsigned int)f2bf(a[5]) << 16);
    o.w = (unsigned int)f2bf(a[6]) | ((unsigned int)f2bf(a[7]) << 16);
    ((uint4*)z)[(size_t)node * LPN + l] = o;
}

// ---------------- bf16 MFMA GEMM: C = epilogue(A @ W + bias) ----------------
// A: M x K bf16 row-major. Wt: Nn x K bf16 (pre-transposed). C: M x Nn bf16.
// BM=128, BK=32, NT n-tiles of 16 per block. 256 threads = 4 waves; wave w
// owns rows [w*32, w*32+32) as 2 m-tiles. B frags read direct from L2-hot Wt.
// bn==0: relu(acc+b); bn==1: relu((acc+b-mu)*g*rsqrt(var+eps)+beta)

template <int NT>
__global__ __launch_bounds__(256) void mfma_gemm_kernel(
    const unsigned short* __restrict__ A, const unsigned short* __restrict__ Wt,
    const float* __restrict__ bias, unsigned short* __restrict__ C,
    int M, int K, int Nn, int bn,
    const float* __restrict__ g, const float* __restrict__ be,
    const float* __restrict__ mu, const float* __restrict__ var) {
    constexpr int BM = 128;
    constexpr int LDA = 48;  // shorts/row: 32 + 16 pad -> 96B rows, 16B-aligned
    __shared__ unsigned short As[BM * LDA];
    const int tid = threadIdx.x;
    const int wv = tid >> 6;
    const int ln = tid & 63;
    const int l15 = ln & 15;
    const int quad = ln >> 4;
    const int row0 = blockIdx.x * BM;
    const int col0 = blockIdx.y * (NT * 16);
    const int sr = tid >> 2;         // staging row (and +64)
    const int sc = (tid & 3) * 8;    // staging col (bf16 units)

    f32x4 acc[2][NT] = {};

    for (int k0 = 0; k0 < K; k0 += 32) {
#pragma unroll
        for (int hh = 0; hh < 2; ++hh) {
            int r = sr + hh * 64;
            int grow = row0 + r;
            if (grow >= M) grow = M - 1;  // clamp; OOB rows never stored
            uint4 v = *(const uint4*)(A + (size_t)grow * K + k0 + sc);
            *(uint4*)(&As[r * LDA + sc]) = v;
        }
        __syncthreads();
        bshort8 af[2];
#pragma unroll
        for (int mt = 0; mt < 2; ++mt) {
            int r = wv * 32 + mt * 16 + l15;
            af[mt] = *(const bshort8*)(&As[r * LDA + quad * 8]);
        }
#pragma unroll
        for (int nt = 0; nt < NT; ++nt) {
            bshort8 bf = *(const bshort8*)(Wt + (size_t)(col0 + nt * 16 + l15) * K + k0 + quad * 8);
            acc[0][nt] = __builtin_amdgcn_mfma_f32_16x16x32_bf16(af[0], bf, acc[0][nt], 0, 0, 0);
            acc[1][nt] = __builtin_amdgcn_mfma_f32_16x16x32_bf16(af[1], bf, acc[1][nt], 0, 0, 0);
        }
        __syncthreads();
    }
#pragma unroll
    for (int nt = 0; nt < NT; ++nt) {
        int c = col0 + nt * 16 + l15;
        float b = bias[c];
        float s = 1.f, sh = b;
        if (bn) {
            float t = g[c] * rsqrtf(var[c] + BN_EPS);
            s = t;
            sh = be[c] - mu[c] * t + b * t;
        }
#pragma unroll
        for (int mt = 0; mt < 2; ++mt) {
            int rbase = row0 + wv * 32 + mt * 16 + quad * 4;
#pragma unroll
            for (int r = 0; r < 4; ++r) {
                int row = rbase + r;
                if (row < M) {
                    float v = fmaxf(acc[mt][nt][r] * s + sh, 0.f);
                    C[(size_t)row * Nn + c] = f2bf(v);
                }
            }
        }
    }
}

// ---------------- classifier: out = h @ wc + bc, K=64, Nout=2, fp32 out ----------------

__global__ __launch_bounds__(256) void classifier_kernel(
    const unsigned short* __restrict__ h, const float* __restrict__ wc,
    const float* __restrict__ bc, float* __restrict__ out, int n) {
    int wave = threadIdx.x >> 6;
    int lane = threadIdx.x & 63;
    int row = blockIdx.x * 4 + wave;
    if (row >= n) return;
    float v = bf2f(h[(size_t)row * 64 + lane]);
    float s0 = v * wc[lane * 2 + 0];
    float s1 = v * wc[lane * 2 + 1];
#pragma unroll
    for (int off = 32; off > 0; off >>= 1) {
        s0 += __shfl_down(s0, off, 64);
        s1 += __shfl_down(s1, off, 64);
    }
    if (lane == 0) {
        out[(size_t)row * 2 + 0] = s0 + bc[0];
        out[(size_t)row * 2 + 1] = s1 + bc[1];
    }
}

// ---------------- launch ----------------

extern "C" void kernel_launch(void* const* d_in, const int* in_sizes, int n_in,
                              void* d_out, int out_size, void* d_ws, size_t ws_size,
                              hipStream_t stream) {
    const float* x = (const float*)d_in[0];
    const int* ei = (const int*)d_in[1];
    const int* src = ei;
    const int* dst = ei + N_EDGES;
    const float* w[4][2];
    const float* b[4][2];
    const float* bng[4];
    const float* bnb[4];
    const float* bnm[4];
    const float* bnv[4];
    int idx = 2;
    for (int i = 0; i < 4; ++i) {
        w[i][0] = (const float*)d_in[idx++];
        b[i][0] = (const float*)d_in[idx++];
        w[i][1] = (const float*)d_in[idx++];
        b[i][1] = (const float*)d_in[idx++];
        bng[i] = (const float*)d_in[idx++];
        bnb[i] = (const float*)d_in[idx++];
        bnm[i] = (const float*)d_in[idx++];
        bnv[i] = (const float*)d_in[idx++];
    }
    const float* wc = (const float*)d_in[idx++];
    const float* bc = (const float*)d_in[idx++];
    float* out = (float*)d_out;

    char* ws = (char*)d_ws;
    size_t off = 0;
    auto alloc = [&](size_t bytes) {
        char* p = ws + off;
        off = (off + bytes + 255) & ~(size_t)255;
        return p;
    };
    int* deg = (int*)alloc((size_t)N_NODES * 4);
    int* rowptr = (int*)alloc((size_t)(N_NODES + 1) * 4);
    int* wptr = (int*)alloc((size_t)N_NODES * 4);
    int* bsum = (int*)alloc((size_t)SCAN_BLOCKS * 4);
    int* col = (int*)alloc((size_t)N_EDGES * 4);
    unsigned short* xbf = (unsigned short*)alloc((size_t)N_NODES * 256 * 2);
    unsigned short* bufA = (unsigned short*)alloc((size_t)N_NODES * 256 * 2);
    unsigned short* bufB = (unsigned short*)alloc((size_t)N_NODES * 256 * 2);
    unsigned short* bufC = (unsigned short*)alloc((size_t)N_NODES * 256 * 2);
    const int dims_in[4] = {256, 128, 256, 128};
    const int dims_h[4] = {128, 256, 128, 64};
    unsigned short* wt[4][2];
    for (int L = 0; L < 4; ++L) {
        wt[L][0] = (unsigned short*)alloc((size_t)dims_in[L] * dims_h[L] * 2);
        wt[L][1] = (unsigned short*)alloc((size_t)dims_h[L] * dims_h[L] * 2);
    }
    (void)ws_size;

    // weight transpose-convert (8 weights, one batched kernel)
    WT8 p;
    for (int L = 0; L < 4; ++L) {
        p.src[L * 2] = w[L][0];     p.dst[L * 2] = wt[L][0];
        p.K[L * 2] = dims_in[L];    p.N[L * 2] = dims_h[L];
        p.src[L * 2 + 1] = w[L][1]; p.dst[L * 2 + 1] = wt[L][1];
        p.K[L * 2 + 1] = dims_h[L]; p.N[L * 2 + 1] = dims_h[L];
    }
    wtconv_kernel<<<dim3(256, 8), 256, 0, stream>>>(p);
    f2bf_kernel<<<(N_NODES * 256 / 4 + 255) / 256, 256, 0, stream>>>(x, xbf, N_NODES * 256);

    // CSR build
    hipMemsetAsync(deg, 0, (size_t)N_NODES * 4, stream);
    hist_kernel<<<3125, 256, 0, stream>>>(dst, deg, N_EDGES);
    scan_reduce_kernel<<<SCAN_BLOCKS, 256, 0, stream>>>(deg, bsum, N_NODES);
    scan_bsum_kernel<<<1, 256, 0, stream>>>(bsum, SCAN_BLOCKS, rowptr, N_NODES);
    scan_apply_kernel<<<SCAN_BLOCKS, 256, 0, stream>>>(deg, bsum, rowptr, wptr, N_NODES);
    scatter_kernel<<<3125, 256, 0, stream>>>(src, dst, wptr, col, N_EDGES);

    const unsigned short* hin = xbf;
    const int gx = (N_NODES + 127) / 128;
    for (int L = 0; L < 4; ++L) {
        int din = dims_in[L];
        int dh = dims_h[L];
        if (din == 256)
            aggregate_bf16_kernel<32><<<(N_NODES + 7) / 8, 256, 0, stream>>>(hin, rowptr, col, bufA, N_NODES);
        else
            aggregate_bf16_kernel<16><<<(N_NODES + 15) / 16, 256, 0, stream>>>(hin, rowptr, col, bufA, N_NODES);
        // GEMM a: M x din -> dh, relu
        if (dh >= 128)
            mfma_gemm_kernel<8><<<dim3(gx, dh / 128), 256, 0, stream>>>(
                bufA, wt[L][0], b[L][0], bufB, N_NODES, din, dh, 0, nullptr, nullptr, nullptr, nullptr);
        else
            mfma_gemm_kernel<4><<<dim3(gx, 1), 256, 0, stream>>>(
                bufA, wt[L][0], b[L][0], bufB, N_NODES, din, dh, 0, nullptr, nullptr, nullptr, nullptr);
        // GEMM b: M x dh -> dh, bias+BN+relu
        if (dh >= 128)
            mfma_gemm_kernel<8><<<dim3(gx, dh / 128), 256, 0, stream>>>(
                bufB, wt[L][1], b[L][1], bufC, N_NODES, dh, dh, 1, bng[L], bnb[L], bnm[L], bnv[L]);
        else
            mfma_gemm_kernel<4><<<dim3(gx, 1), 256, 0, stream>>>(
                bufB, wt[L][1], b[L][1], bufC, N_NODES, dh, dh, 1, bng[L], bnb[L], bnm[L], bnv[L]);
        hin = bufC;
    }
    classifier_kernel<<<(N_NODES + 3) / 4, 256, 0, stream>>>(bufC, wc, bc, out, N_NODES);
}

// Round 4
// 610.350 us; speedup vs baseline: 2.0430x; 1.1357x over previous
//
#include <hip/hip_runtime.h>

#define N_NODES 50000
#define N_EDGES 800000
#define BN_EPS 1e-5f
#define SCAN_BLOCKS 196  // ceil(50000/256)

typedef __attribute__((ext_vector_type(8))) short bshort8;
typedef __attribute__((ext_vector_type(4))) float f32x4;

__device__ inline float bf2f(unsigned int u16) {
    return __uint_as_float(u16 << 16);
}
__device__ inline unsigned short f2bf(float f) {
    unsigned int u = __float_as_uint(f);
    u = (u + 0x7FFFu + ((u >> 16) & 1u)) >> 16;
    return (unsigned short)u;
}

// ---------------- CSR build ----------------

__global__ void hist_kernel(const int* __restrict__ dst, int* __restrict__ deg, int e) {
    int i = blockIdx.x * blockDim.x + threadIdx.x;
    int stride = gridDim.x * blockDim.x;
    for (; i < e; i += stride) atomicAdd(&deg[dst[i]], 1);
}

__device__ inline int block_exscan256(int v, int tid, int* total) {
    int lane = tid & 63;
    int wave = tid >> 6;
    int incl = v;
#pragma unroll
    for (int off = 1; off < 64; off <<= 1) {
        int t = __shfl_up(incl, off, 64);
        if (lane >= off) incl += t;
    }
    __shared__ int wsum[4];
    if (lane == 63) wsum[wave] = incl;
    __syncthreads();
    int w0 = wsum[0], w1 = wsum[1], w2 = wsum[2], w3 = wsum[3];
    __syncthreads();
    int wofs = (wave > 0 ? w0 : 0) + (wave > 1 ? w1 : 0) + (wave > 2 ? w2 : 0);
    *total = w0 + w1 + w2 + w3;
    return wofs + incl - v;
}

__global__ __launch_bounds__(256) void scan_reduce_kernel(const int* __restrict__ deg,
                                                          int* __restrict__ bsum, int n) {
    int tid = threadIdx.x;
    int i = blockIdx.x * 256 + tid;
    int v = (i < n) ? deg[i] : 0;
    int lane = tid & 63;
    int wave = tid >> 6;
#pragma unroll
    for (int off = 32; off > 0; off >>= 1) v += __shfl_down(v, off, 64);
    __shared__ int wsum[4];
    if (lane == 0) wsum[wave] = v;
    __syncthreads();
    if (tid == 0) bsum[blockIdx.x] = wsum[0] + wsum[1] + wsum[2] + wsum[3];
}

__global__ __launch_bounds__(256) void scan_bsum_kernel(int* __restrict__ bsum, int B,
                                                        int* __restrict__ rowptr, int n) {
    int tid = threadIdx.x;
    int v = (tid < B) ? bsum[tid] : 0;
    int total;
    int excl = block_exscan256(v, tid, &total);
    if (tid < B) bsum[tid] = excl;
    if (tid == 0) rowptr[n] = total;
}

__global__ __launch_bounds__(256) void scan_apply_kernel(const int* __restrict__ deg,
                                                         const int* __restrict__ bsum,
                                                         int* __restrict__ rowptr,
                                                         int* __restrict__ wptr, int n) {
    int tid = threadIdx.x;
    int i = blockIdx.x * 256 + tid;
    int v = (i < n) ? deg[i] : 0;
    int total;
    int excl = block_exscan256(v, tid, &total);
    if (i < n) {
        int r = bsum[blockIdx.x] + excl;
        rowptr[i] = r;
        wptr[i] = r;
    }
}

__global__ void scatter_kernel(const int* __restrict__ src, const int* __restrict__ dst,
                               int* __restrict__ wptr, int* __restrict__ col, int e) {
    int i = blockIdx.x * blockDim.x + threadIdx.x;
    int stride = gridDim.x * blockDim.x;
    for (; i < e; i += stride) {
        int d = dst[i];
        int p = atomicAdd(&wptr[d], 1);
        col[p] = src[i];
    }
}

// ---------------- conversions ----------------

__global__ __launch_bounds__(256) void f2bf_kernel(const float* __restrict__ src,
                                                   unsigned short* __restrict__ dst, int n) {
    int i = (blockIdx.x * 256 + threadIdx.x) * 4;
    if (i >= n) return;
    float4 v = *(const float4*)(src + i);
    ushort4 o;
    o.x = f2bf(v.x); o.y = f2bf(v.y); o.z = f2bf(v.z); o.w = f2bf(v.w);
    *(ushort4*)(dst + i) = o;
}

struct WT8 {
    const float* src[8];
    unsigned short* dst[8];
    int K[8];
    int N[8];
};

// W[K][N] fp32 -> Wt[N][K] bf16 (N,K are powers of two)
__global__ __launch_bounds__(256) void wtconv_kernel(WT8 p) {
    int wi = blockIdx.y;
    int K = p.K[wi], N = p.N[wi];
    int idx = blockIdx.x * 256 + threadIdx.x;
    if (idx >= K * N) return;
    int logn = 31 - __clz(N);
    int n = idx & (N - 1);
    int k = idx >> logn;
    p.dst[wi][(size_t)n * K + k] = f2bf(p.src[wi][idx]);
}

// ---------------- aggregation (bf16): z[i] = h[i] + sum_{j in N(i)} h[j] ----------------
// LPN lanes per node, each lane owns 8 bf16 feats (one uint4).
// RELU=true: epilogue z = relu(z + bias) (the commuted GIN first-linear epilogue).

__device__ inline void acc8(uint4 v, float* a) {
    a[0] += bf2f(v.x & 0xFFFFu); a[1] += __uint_as_float(v.x & 0xFFFF0000u);
    a[2] += bf2f(v.y & 0xFFFFu); a[3] += __uint_as_float(v.y & 0xFFFF0000u);
    a[4] += bf2f(v.z & 0xFFFFu); a[5] += __uint_as_float(v.z & 0xFFFF0000u);
    a[6] += bf2f(v.w & 0xFFFFu); a[7] += __uint_as_float(v.w & 0xFFFF0000u);
}

template <int LPN, bool RELU>
__global__ __launch_bounds__(256) void aggregate_bf16_kernel(
    const unsigned short* __restrict__ h, const int* __restrict__ rowptr,
    const int* __restrict__ col, const float* __restrict__ bias,
    unsigned short* __restrict__ z, int n) {
    const int gpb = 256 / LPN;
    int gid = threadIdx.x / LPN;
    int l = threadIdx.x % LPN;
    int node = blockIdx.x * gpb + gid;
    if (node >= n) return;
    const uint4* hv = (const uint4*)h;
    float a[8] = {};
    acc8(hv[(size_t)node * LPN + l], a);  // self
    int s = rowptr[node], epos = rowptr[node + 1];
    for (int e = s; e < epos; ++e) {
        int j = col[e];
        acc8(hv[(size_t)j * LPN + l], a);
    }
    if (RELU) {
        float4 b0 = *(const float4*)(bias + l * 8);
        float4 b1 = *(const float4*)(bias + l * 8 + 4);
        a[0] = fmaxf(a[0] + b0.x, 0.f); a[1] = fmaxf(a[1] + b0.y, 0.f);
        a[2] = fmaxf(a[2] + b0.z, 0.f); a[3] = fmaxf(a[3] + b0.w, 0.f);
        a[4] = fmaxf(a[4] + b1.x, 0.f); a[5] = fmaxf(a[5] + b1.y, 0.f);
        a[6] = fmaxf(a[6] + b1.z, 0.f); a[7] = fmaxf(a[7] + b1.w, 0.f);
    }
    uint4 o;
    o.x = (unsigned int)f2bf(a[0]) | ((unsigned int)f2bf(a[1]) << 16);
    o.y = (unsigned int)f2bf(a[2]) | ((unsigned int)f2bf(a[3]) << 16);
    o.z = (unsigned int)f2bf(a[4]) | ((unsigned int)f2bf(a[5]) << 16);
    o.w = (unsigned int)f2bf(a[6]) | ((unsigned int)f2bf(a[7]) << 16);
    ((uint4*)z)[(size_t)node * LPN + l] = o;
}

// ---------------- bf16 MFMA GEMM: C = epilogue(A @ W [+ bias]) ----------------
// A: M x K bf16 row-major. Wt: Nn x K bf16 (pre-transposed). C: M x Nn bf16.
// BM=128, BK=32, NT n-tiles of 16 per block. 256 threads = 4 waves.
// mode 0: relu(acc+b); mode 1: relu((acc+b-mu)*g*rsqrt(var+eps)+beta); mode 2: raw acc

template <int NT>
__global__ __launch_bounds__(256) void mfma_gemm_kernel(
    const unsigned short* __restrict__ A, const unsigned short* __restrict__ Wt,
    const float* __restrict__ bias, unsigned short* __restrict__ C,
    int M, int K, int Nn, int mode,
    const float* __restrict__ g, const float* __restrict__ be,
    const float* __restrict__ mu, const float* __restrict__ var) {
    constexpr int BM = 128;
    constexpr int LDA = 48;  // shorts/row: 32 + 16 pad -> 96B rows, 16B-aligned
    __shared__ unsigned short As[BM * LDA];
    const int tid = threadIdx.x;
    const int wv = tid >> 6;
    const int ln = tid & 63;
    const int l15 = ln & 15;
    const int quad = ln >> 4;
    const int row0 = blockIdx.x * BM;
    const int col0 = blockIdx.y * (NT * 16);
    const int sr = tid >> 2;
    const int sc = (tid & 3) * 8;

    f32x4 acc[2][NT] = {};

    for (int k0 = 0; k0 < K; k0 += 32) {
#pragma unroll
        for (int hh = 0; hh < 2; ++hh) {
            int r = sr + hh * 64;
            int grow = row0 + r;
            if (grow >= M) grow = M - 1;  // clamp; OOB rows never stored
            uint4 v = *(const uint4*)(A + (size_t)grow * K + k0 + sc);
            *(uint4*)(&As[r * LDA + sc]) = v;
        }
        __syncthreads();
        bshort8 af[2];
#pragma unroll
        for (int mt = 0; mt < 2; ++mt) {
            int r = wv * 32 + mt * 16 + l15;
            af[mt] = *(const bshort8*)(&As[r * LDA + quad * 8]);
        }
#pragma unroll
        for (int nt = 0; nt < NT; ++nt) {
            bshort8 bf = *(const bshort8*)(Wt + (size_t)(col0 + nt * 16 + l15) * K + k0 + quad * 8);
            acc[0][nt] = __builtin_amdgcn_mfma_f32_16x16x32_bf16(af[0], bf, acc[0][nt], 0, 0, 0);
            acc[1][nt] = __builtin_amdgcn_mfma_f32_16x16x32_bf16(af[1], bf, acc[1][nt], 0, 0, 0);
        }
        __syncthreads();
    }
#pragma unroll
    for (int nt = 0; nt < NT; ++nt) {
        int c = col0 + nt * 16 + l15;
        float s = 1.f, sh = 0.f;
        if (mode == 0) {
            sh = bias[c];
        } else if (mode == 1) {
            float b = bias[c];
            float t = g[c] * rsqrtf(var[c] + BN_EPS);
            s = t;
            sh = be[c] - mu[c] * t + b * t;
        }
#pragma unroll
        for (int mt = 0; mt < 2; ++mt) {
            int rbase = row0 + wv * 32 + mt * 16 + quad * 4;
#pragma unroll
            for (int r = 0; r < 4; ++r) {
                int row = rbase + r;
                if (row < M) {
                    float v = acc[mt][nt][r] * s + sh;
                    if (mode != 2) v = fmaxf(v, 0.f);
                    C[(size_t)row * Nn + c] = f2bf(v);
                }
            }
        }
    }
}

// ---------------- classifier: out = h @ wc + bc, K=64, Nout=2, fp32 out ----------------

__global__ __launch_bounds__(256) void classifier_kernel(
    const unsigned short* __restrict__ h, const float* __restrict__ wc,
    const float* __restrict__ bc, float* __restrict__ out, int n) {
    int wave = threadIdx.x >> 6;
    int lane = threadIdx.x & 63;
    int row = blockIdx.x * 4 + wave;
    if (row >= n) return;
    float v = bf2f(h[(size_t)row * 64 + lane]);
    float s0 = v * wc[lane * 2 + 0];
    float s1 = v * wc[lane * 2 + 1];
#pragma unroll
    for (int off = 32; off > 0; off >>= 1) {
        s0 += __shfl_down(s0, off, 64);
        s1 += __shfl_down(s1, off, 64);
    }
    if (lane == 0) {
        out[(size_t)row * 2 + 0] = s0 + bc[0];
        out[(size_t)row * 2 + 1] = s1 + bc[1];
    }
}

// ---------------- launch ----------------

extern "C" void kernel_launch(void* const* d_in, const int* in_sizes, int n_in,
                              void* d_out, int out_size, void* d_ws, size_t ws_size,
                              hipStream_t stream) {
    const float* x = (const float*)d_in[0];
    const int* ei = (const int*)d_in[1];
    const int* src = ei;
    const int* dst = ei + N_EDGES;
    const float* w[4][2];
    const float* b[4][2];
    const float* bng[4];
    const float* bnb[4];
    const float* bnm[4];
    const float* bnv[4];
    int idx = 2;
    for (int i = 0; i < 4; ++i) {
        w[i][0] = (const float*)d_in[idx++];
        b[i][0] = (const float*)d_in[idx++];
        w[i][1] = (const float*)d_in[idx++];
        b[i][1] = (const float*)d_in[idx++];
        bng[i] = (const float*)d_in[idx++];
        bnb[i] = (const float*)d_in[idx++];
        bnm[i] = (const float*)d_in[idx++];
        bnv[i] = (const float*)d_in[idx++];
    }
    const float* wc = (const float*)d_in[idx++];
    const float* bc = (const float*)d_in[idx++];
    float* out = (float*)d_out;

    char* ws = (char*)d_ws;
    size_t off = 0;
    auto alloc = [&](size_t bytes) {
        char* p = ws + off;
        off = (off + bytes + 255) & ~(size_t)255;
        return p;
    };
    int* deg = (int*)alloc((size_t)N_NODES * 4);
    int* rowptr = (int*)alloc((size_t)(N_NODES + 1) * 4);
    int* wptr = (int*)alloc((size_t)N_NODES * 4);
    int* bsum = (int*)alloc((size_t)SCAN_BLOCKS * 4);
    int* col = (int*)alloc((size_t)N_EDGES * 4);
    unsigned short* xbf = (unsigned short*)alloc((size_t)N_NODES * 256 * 2);
    unsigned short* bufA = (unsigned short*)alloc((size_t)N_NODES * 256 * 2);
    unsigned short* bufB = (unsigned short*)alloc((size_t)N_NODES * 256 * 2);
    unsigned short* bufC = (unsigned short*)alloc((size_t)N_NODES * 256 * 2);
    const int dims_in[4] = {256, 128, 256, 128};
    const int dims_h[4] = {128, 256, 128, 64};
    unsigned short* wt[4][2];
    for (int L = 0; L < 4; ++L) {
        wt[L][0] = (unsigned short*)alloc((size_t)dims_in[L] * dims_h[L] * 2);
        wt[L][1] = (unsigned short*)alloc((size_t)dims_h[L] * dims_h[L] * 2);
    }
    (void)ws_size;

    // weight transpose-convert + input convert
    WT8 p;
    for (int L = 0; L < 4; ++L) {
        p.src[L * 2] = w[L][0];     p.dst[L * 2] = wt[L][0];
        p.K[L * 2] = dims_in[L];    p.N[L * 2] = dims_h[L];
        p.src[L * 2 + 1] = w[L][1]; p.dst[L * 2 + 1] = wt[L][1];
        p.K[L * 2 + 1] = dims_h[L]; p.N[L * 2 + 1] = dims_h[L];
    }
    wtconv_kernel<<<dim3(256, 8), 256, 0, stream>>>(p);
    f2bf_kernel<<<(N_NODES * 256 / 4 + 255) / 256, 256, 0, stream>>>(x, xbf, N_NODES * 256);

    // CSR build
    hipMemsetAsync(deg, 0, (size_t)N_NODES * 4, stream);
    hist_kernel<<<3125, 256, 0, stream>>>(dst, deg, N_EDGES);
    scan_reduce_kernel<<<SCAN_BLOCKS, 256, 0, stream>>>(deg, bsum, N_NODES);
    scan_bsum_kernel<<<1, 256, 0, stream>>>(bsum, SCAN_BLOCKS, rowptr, N_NODES);
    scan_apply_kernel<<<SCAN_BLOCKS, 256, 0, stream>>>(deg, bsum, rowptr, wptr, N_NODES);
    scatter_kernel<<<3125, 256, 0, stream>>>(src, dst, wptr, col, N_EDGES);

    const int gx = (N_NODES + 127) / 128;
    const int M = N_NODES;

    // ---- Layer 1 (commuted: GEMM1 256->128, agg@128 + bias+relu, GEMM2) ----
    mfma_gemm_kernel<8><<<dim3(gx, 1), 256, 0, stream>>>(
        xbf, wt[0][0], nullptr, bufA, M, 256, 128, 2, nullptr, nullptr, nullptr, nullptr);
    aggregate_bf16_kernel<16, true><<<(N_NODES + 15) / 16, 256, 0, stream>>>(
        bufA, rowptr, col, b[0][0], bufB, N_NODES);
    mfma_gemm_kernel<8><<<dim3(gx, 1), 256, 0, stream>>>(
        bufB, wt[0][1], b[0][1], bufC, M, 128, 128, 1, bng[0], bnb[0], bnm[0], bnv[0]);

    // ---- Layer 2 (agg-first: agg@128, GEMM1 128->256 relu, GEMM2 256->256 BN) ----
    aggregate_bf16_kernel<16, false><<<(N_NODES + 15) / 16, 256, 0, stream>>>(
        bufC, rowptr, col, nullptr, bufA, N_NODES);
    mfma_gemm_kernel<8><<<dim3(gx, 2), 256, 0, stream>>>(
        bufA, wt[1][0], b[1][0], bufB, M, 128, 256, 0, nullptr, nullptr, nullptr, nullptr);
    mfma_gemm_kernel<8><<<dim3(gx, 2), 256, 0, stream>>>(
        bufB, wt[1][1], b[1][1], bufC, M, 256, 256, 1, bng[1], bnb[1], bnm[1], bnv[1]);

    // ---- Layer 3 (commuted: GEMM1 256->128, agg@128 + bias+relu, GEMM2) ----
    mfma_gemm_kernel<8><<<dim3(gx, 1), 256, 0, stream>>>(
        bufC, wt[2][0], nullptr, bufA, M, 256, 128, 2, nullptr, nullptr, nullptr, nullptr);
    aggregate_bf16_kernel<16, true><<<(N_NODES + 15) / 16, 256, 0, stream>>>(
        bufA, rowptr, col, b[2][0], bufB, N_NODES);
    mfma_gemm_kernel<8><<<dim3(gx, 1), 256, 0, stream>>>(
        bufB, wt[2][1], b[2][1], bufC, M, 128, 128, 1, bng[2], bnb[2], bnm[2], bnv[2]);

    // ---- Layer 4 (commuted: GEMM1 128->64, agg@64 + bias+relu, GEMM2 64->64 BN) ----
    mfma_gemm_kernel<4><<<dim3(gx, 1), 256, 0, stream>>>(
        bufC, wt[3][0], nullptr, bufA, M, 128, 64, 2, nullptr, nullptr, nullptr, nullptr);
    aggregate_bf16_kernel<8, true><<<(N_NODES + 31) / 32, 256, 0, stream>>>(
        bufA, rowptr, col, b[3][0], bufB, N_NODES);
    mfma_gemm_kernel<4><<<dim3(gx, 1), 256, 0, stream>>>(
        bufB, wt[3][1], b[3][1], bufC, M, 64, 64, 1, bng[3], bnb[3], bnm[3], bnv[3]);

    classifier_kernel<<<(N_NODES + 3) / 4, 256, 0, stream>>>(bufC, wc, bc, out, N_NODES);
}

// Round 5
// 571.341 us; speedup vs baseline: 2.1825x; 1.0683x over previous
//
#include <hip/hip_runtime.h>

#define N_NODES 50000
#define N_EDGES 800000
#define BN_EPS 1e-5f
#define SCAN_BLOCKS 196  // ceil(50000/256)

typedef __attribute__((ext_vector_type(8))) short bshort8;
typedef __attribute__((ext_vector_type(4))) float f32x4;

__device__ inline float bf2f(unsigned int u16) {
    return __uint_as_float(u16 << 16);
}
__device__ inline unsigned short f2bf(float f) {
    unsigned int u = __float_as_uint(f);
    u = (u + 0x7FFFu + ((u >> 16) & 1u)) >> 16;
    return (unsigned short)u;
}

// ---------------- CSR build ----------------

__global__ void hist_kernel(const int* __restrict__ dst, int* __restrict__ deg, int e) {
    int i = blockIdx.x * blockDim.x + threadIdx.x;
    int stride = gridDim.x * blockDim.x;
    for (; i < e; i += stride) atomicAdd(&deg[dst[i]], 1);
}

__device__ inline int block_exscan256(int v, int tid, int* total) {
    int lane = tid & 63;
    int wave = tid >> 6;
    int incl = v;
#pragma unroll
    for (int off = 1; off < 64; off <<= 1) {
        int t = __shfl_up(incl, off, 64);
        if (lane >= off) incl += t;
    }
    __shared__ int wsum[4];
    if (lane == 63) wsum[wave] = incl;
    __syncthreads();
    int w0 = wsum[0], w1 = wsum[1], w2 = wsum[2], w3 = wsum[3];
    __syncthreads();
    int wofs = (wave > 0 ? w0 : 0) + (wave > 1 ? w1 : 0) + (wave > 2 ? w2 : 0);
    *total = w0 + w1 + w2 + w3;
    return wofs + incl - v;
}

__global__ __launch_bounds__(256) void scan_reduce_kernel(const int* __restrict__ deg,
                                                          int* __restrict__ bsum, int n) {
    int tid = threadIdx.x;
    int i = blockIdx.x * 256 + tid;
    int v = (i < n) ? deg[i] : 0;
    int lane = tid & 63;
    int wave = tid >> 6;
#pragma unroll
    for (int off = 32; off > 0; off >>= 1) v += __shfl_down(v, off, 64);
    __shared__ int wsum[4];
    if (lane == 0) wsum[wave] = v;
    __syncthreads();
    if (tid == 0) bsum[blockIdx.x] = wsum[0] + wsum[1] + wsum[2] + wsum[3];
}

__global__ __launch_bounds__(256) void scan_bsum_kernel(int* __restrict__ bsum, int B,
                                                        int* __restrict__ rowptr, int n) {
    int tid = threadIdx.x;
    int v = (tid < B) ? bsum[tid] : 0;
    int total;
    int excl = block_exscan256(v, tid, &total);
    if (tid < B) bsum[tid] = excl;
    if (tid == 0) rowptr[n] = total;
}

__global__ __launch_bounds__(256) void scan_apply_kernel(const int* __restrict__ deg,
                                                         const int* __restrict__ bsum,
                                                         int* __restrict__ rowptr,
                                                         int* __restrict__ wptr, int n) {
    int tid = threadIdx.x;
    int i = blockIdx.x * 256 + tid;
    int v = (i < n) ? deg[i] : 0;
    int total;
    int excl = block_exscan256(v, tid, &total);
    if (i < n) {
        int r = bsum[blockIdx.x] + excl;
        rowptr[i] = r;
        wptr[i] = r;
    }
}

__global__ void scatter_kernel(const int* __restrict__ src, const int* __restrict__ dst,
                               int* __restrict__ wptr, int* __restrict__ col, int e) {
    int i = blockIdx.x * blockDim.x + threadIdx.x;
    int stride = gridDim.x * blockDim.x;
    for (; i < e; i += stride) {
        int d = dst[i];
        int p = atomicAdd(&wptr[d], 1);
        col[p] = src[i];
    }
}

// ---------------- conversions ----------------

struct WT8 {
    const float* src[8];
    unsigned short* dst[8];
    int K[8];
    int N[8];
};

// W[K][N] fp32 -> Wt[N][K] bf16 (N,K are powers of two)
__global__ __launch_bounds__(256) void wtconv_kernel(WT8 p) {
    int wi = blockIdx.y;
    int K = p.K[wi], N = p.N[wi];
    int idx = blockIdx.x * 256 + threadIdx.x;
    if (idx >= K * N) return;
    int logn = 31 - __clz(N);
    int n = idx & (N - 1);
    int k = idx >> logn;
    p.dst[wi][(size_t)n * K + k] = f2bf(p.src[wi][idx]);
}

// ---------------- aggregation (bf16): z[i] = h[i] + sum_{j in N(i)} h[j] ----------------

__device__ inline void acc8(uint4 v, float* a) {
    a[0] += bf2f(v.x & 0xFFFFu); a[1] += __uint_as_float(v.x & 0xFFFF0000u);
    a[2] += bf2f(v.y & 0xFFFFu); a[3] += __uint_as_float(v.y & 0xFFFF0000u);
    a[4] += bf2f(v.z & 0xFFFFu); a[5] += __uint_as_float(v.z & 0xFFFF0000u);
    a[6] += bf2f(v.w & 0xFFFFu); a[7] += __uint_as_float(v.w & 0xFFFF0000u);
}

template <int LPN, bool RELU>
__global__ __launch_bounds__(256) void aggregate_bf16_kernel(
    const unsigned short* __restrict__ h, const int* __restrict__ rowptr,
    const int* __restrict__ col, const float* __restrict__ bias,
    unsigned short* __restrict__ z, int n) {
    const int gpb = 256 / LPN;
    int gid = threadIdx.x / LPN;
    int l = threadIdx.x % LPN;
    int node = blockIdx.x * gpb + gid;
    if (node >= n) return;
    const uint4* hv = (const uint4*)h;
    float a[8] = {};
    acc8(hv[(size_t)node * LPN + l], a);  // self
    int s = rowptr[node], epos = rowptr[node + 1];
    for (int e = s; e < epos; ++e) {
        int j = col[e];
        acc8(hv[(size_t)j * LPN + l], a);
    }
    if (RELU) {
        float4 b0 = *(const float4*)(bias + l * 8);
        float4 b1 = *(const float4*)(bias + l * 8 + 4);
        a[0] = fmaxf(a[0] + b0.x, 0.f); a[1] = fmaxf(a[1] + b0.y, 0.f);
        a[2] = fmaxf(a[2] + b0.z, 0.f); a[3] = fmaxf(a[3] + b0.w, 0.f);
        a[4] = fmaxf(a[4] + b1.x, 0.f); a[5] = fmaxf(a[5] + b1.y, 0.f);
        a[6] = fmaxf(a[6] + b1.z, 0.f); a[7] = fmaxf(a[7] + b1.w, 0.f);
    }
    uint4 o;
    o.x = (unsigned int)f2bf(a[0]) | ((unsigned int)f2bf(a[1]) << 16);
    o.y = (unsigned int)f2bf(a[2]) | ((unsigned int)f2bf(a[3]) << 16);
    o.z = (unsigned int)f2bf(a[4]) | ((unsigned int)f2bf(a[5]) << 16);
    o.w = (unsigned int)f2bf(a[6]) | ((unsigned int)f2bf(a[7]) << 16);
    ((uint4*)z)[(size_t)node * LPN + l] = o;
}

// ---------------- bf16 MFMA GEMM v2 ----------------
// C = epilogue(A @ Wt^T). A: M x K (bf16, or fp32 if F32A). Wt: Nn x K bf16.
// BM=128, BK=64, BN=NT*16. 256 thr = 4 waves; wave wv owns rows wv*32..+31.
// Software-pipelined: global->reg prefetch of tile k+1 overlaps MFMA of tile k.
// A and B tiles staged in LDS (B loaded once per block, not per wave).
// Epilogue staged through LDS -> fully coalesced 16B/lane global stores.
// mode 0: relu(acc+b); 1: relu((acc+b-mu)*g*rsqrt(var+eps)+be); 2: raw acc

template <int NT, bool F32A>
__global__ __launch_bounds__(256) void mfma_gemm2_kernel(
    const void* __restrict__ Ain, const unsigned short* __restrict__ Wt,
    const float* __restrict__ bias, unsigned short* __restrict__ C,
    int M, int K, int Nn, int mode,
    const float* __restrict__ g, const float* __restrict__ be,
    const float* __restrict__ mu, const float* __restrict__ var) {
    constexpr int BM = 128, BK = 64;
    constexpr int BN = NT * 16;
    constexpr int LDA = BK + 8;   // 72 shorts = 144B rows: 16B-aligned, 4-bank rotation
    constexpr int LDB = BK + 8;
    constexpr int LDE = BN + 8;   // epilogue stride, 16B-aligned
    constexpr int NB_LD = (BN * BK / 8) / 256;  // uint4 loads/thread for B (4 or 2)
    __shared__ __align__(16) unsigned short smem[BM * LDA + BN * LDB];
    unsigned short* As = smem;
    unsigned short* Bs = smem + BM * LDA;
    unsigned short* Ep = smem;  // epilogue reuses tile space (BM*LDE fits)

    const int tid = threadIdx.x;
    const int wv = tid >> 6;
    const int ln = tid & 63;
    const int l15 = ln & 15;
    const int quad = ln >> 4;
    const int row0 = blockIdx.x * BM;
    const int col0 = blockIdx.y * BN;

    const unsigned short* A16 = (const unsigned short*)Ain;
    const float* A32 = (const float*)Ain;

    uint4 Ar[4], Br[NB_LD];

    auto loadA = [&](int k0) {
#pragma unroll
        for (int u = 0; u < 4; ++u) {
            int idx2 = tid + 256 * u;
            int r = idx2 >> 3, cg = (idx2 & 7) * 8;
            int gr = row0 + r;
            if (gr >= M) gr = M - 1;  // clamp; OOB rows never stored
            if (F32A) {
                float4 f0 = *(const float4*)(A32 + (size_t)gr * K + k0 + cg);
                float4 f1 = *(const float4*)(A32 + (size_t)gr * K + k0 + cg + 4);
                uint4 o;
                o.x = (unsigned)f2bf(f0.x) | ((unsigned)f2bf(f0.y) << 16);
                o.y = (unsigned)f2bf(f0.z) | ((unsigned)f2bf(f0.w) << 16);
                o.z = (unsigned)f2bf(f1.x) | ((unsigned)f2bf(f1.y) << 16);
                o.w = (unsigned)f2bf(f1.z) | ((unsigned)f2bf(f1.w) << 16);
                Ar[u] = o;
            } else {
                Ar[u] = *(const uint4*)(A16 + (size_t)gr * K + k0 + cg);
            }
        }
    };
    auto loadB = [&](int k0) {
#pragma unroll
        for (int u = 0; u < NB_LD; ++u) {
            int idx2 = tid + 256 * u;
            int r = idx2 >> 3, cg = (idx2 & 7) * 8;
            Br[u] = *(const uint4*)(Wt + (size_t)(col0 + r) * K + k0 + cg);
        }
    };
    auto stage = [&]() {
#pragma unroll
        for (int u = 0; u < 4; ++u) {
            int idx2 = tid + 256 * u;
            int r = idx2 >> 3, cg = (idx2 & 7) * 8;
            *(uint4*)(&As[r * LDA + cg]) = Ar[u];
        }
#pragma unroll
        for (int u = 0; u < NB_LD; ++u) {
            int idx2 = tid + 256 * u;
            int r = idx2 >> 3, cg = (idx2 & 7) * 8;
            *(uint4*)(&Bs[r * LDB + cg]) = Br[u];
        }
    };

    f32x4 acc[2][NT] = {};
    const int KT = K >> 6;
    loadA(0);
    loadB(0);
    for (int kt = 0; kt < KT; ++kt) {
        if (kt > 0) __syncthreads();  // previous compute done before LDS overwrite
        stage();
        __syncthreads();
        if (kt + 1 < KT) {            // prefetch next tile; vmcnt absorbed at next stage()
            loadA((kt + 1) * 64);
            loadB((kt + 1) * 64);
        }
#pragma unroll
        for (int kh = 0; kh < 2; ++kh) {
            bshort8 af[2];
#pragma unroll
            for (int mt = 0; mt < 2; ++mt)
                af[mt] = *(const bshort8*)(&As[(wv * 32 + mt * 16 + l15) * LDA + kh * 32 + quad * 8]);
#pragma unroll
            for (int nt = 0; nt < NT; ++nt) {
                bshort8 bf = *(const bshort8*)(&Bs[(nt * 16 + l15) * LDB + kh * 32 + quad * 8]);
                acc[0][nt] = __builtin_amdgcn_mfma_f32_16x16x32_bf16(af[0], bf, acc[0][nt], 0, 0, 0);
                acc[1][nt] = __builtin_amdgcn_mfma_f32_16x16x32_bf16(af[1], bf, acc[1][nt], 0, 0, 0);
            }
        }
    }

    // epilogue: scale/shift/relu -> LDS -> coalesced 16B stores
    __syncthreads();
#pragma unroll
    for (int nt = 0; nt < NT; ++nt) {
        int c = col0 + nt * 16 + l15;
        float s = 1.f, sh = 0.f;
        if (mode == 0) {
            sh = bias[c];
        } else if (mode == 1) {
            float t = g[c] * rsqrtf(var[c] + BN_EPS);
            s = t;
            sh = be[c] - mu[c] * t + bias[c] * t;
        }
#pragma unroll
        for (int mt = 0; mt < 2; ++mt) {
            int rl = wv * 32 + mt * 16 + quad * 4;
#pragma unroll
            for (int r = 0; r < 4; ++r) {
                float v = acc[mt][nt][r] * s + sh;
                if (mode != 2) v = fmaxf(v, 0.f);
                Ep[(rl + r) * LDE + nt * 16 + l15] = f2bf(v);
            }
        }
    }
    __syncthreads();
    constexpr int CGR = BN / 8;           // uint4 per output row
    constexpr int NU = BM * CGR / 256;    // uint4 per thread
#pragma unroll
    for (int u = 0; u < NU; ++u) {
        int idx2 = tid + 256 * u;
        int r = idx2 / CGR, cg = (idx2 % CGR) * 8;
        int grow = row0 + r;
        if (grow < M)
            *(uint4*)(C + (size_t)grow * Nn + col0 + cg) = *(const uint4*)(&Ep[r * LDE + cg]);
    }
}

// ---------------- classifier: out = h @ wc + bc, K=64, Nout=2, fp32 out ----------------

__global__ __launch_bounds__(256) void classifier_kernel(
    const unsigned short* __restrict__ h, const float* __restrict__ wc,
    const float* __restrict__ bc, float* __restrict__ out, int n) {
    int wave = threadIdx.x >> 6;
    int lane = threadIdx.x & 63;
    int row = blockIdx.x * 4 + wave;
    if (row >= n) return;
    float v = bf2f(h[(size_t)row * 64 + lane]);
    float s0 = v * wc[lane * 2 + 0];
    float s1 = v * wc[lane * 2 + 1];
#pragma unroll
    for (int off = 32; off > 0; off >>= 1) {
        s0 += __shfl_down(s0, off, 64);
        s1 += __shfl_down(s1, off, 64);
    }
    if (lane == 0) {
        out[(size_t)row * 2 + 0] = s0 + bc[0];
        out[(size_t)row * 2 + 1] = s1 + bc[1];
    }
}

// ---------------- launch ----------------

extern "C" void kernel_launch(void* const* d_in, const int* in_sizes, int n_in,
                              void* d_out, int out_size, void* d_ws, size_t ws_size,
                              hipStream_t stream) {
    const float* x = (const float*)d_in[0];
    const int* ei = (const int*)d_in[1];
    const int* src = ei;
    const int* dst = ei + N_EDGES;
    const float* w[4][2];
    const float* b[4][2];
    const float* bng[4];
    const float* bnb[4];
    const float* bnm[4];
    const float* bnv[4];
    int idx = 2;
    for (int i = 0; i < 4; ++i) {
        w[i][0] = (const float*)d_in[idx++];
        b[i][0] = (const float*)d_in[idx++];
        w[i][1] = (const float*)d_in[idx++];
        b[i][1] = (const float*)d_in[idx++];
        bng[i] = (const float*)d_in[idx++];
        bnb[i] = (const float*)d_in[idx++];
        bnm[i] = (const float*)d_in[idx++];
        bnv[i] = (const float*)d_in[idx++];
    }
    const float* wc = (const float*)d_in[idx++];
    const float* bc = (const float*)d_in[idx++];
    float* out = (float*)d_out;

    char* ws = (char*)d_ws;
    size_t off = 0;
    auto alloc = [&](size_t bytes) {
        char* p = ws + off;
        off = (off + bytes + 255) & ~(size_t)255;
        return p;
    };
    int* deg = (int*)alloc((size_t)N_NODES * 4);
    int* rowptr = (int*)alloc((size_t)(N_NODES + 1) * 4);
    int* wptr = (int*)alloc((size_t)N_NODES * 4);
    int* bsum = (int*)alloc((size_t)SCAN_BLOCKS * 4);
    int* col = (int*)alloc((size_t)N_EDGES * 4);
    unsigned short* bufA = (unsigned short*)alloc((size_t)N_NODES * 256 * 2);
    unsigned short* bufB = (unsigned short*)alloc((size_t)N_NODES * 256 * 2);
    unsigned short* bufC = (unsigned short*)alloc((size_t)N_NODES * 256 * 2);
    const int dims_in[4] = {256, 128, 256, 128};
    const int dims_h[4] = {128, 256, 128, 64};
    unsigned short* wt[4][2];
    for (int L = 0; L < 4; ++L) {
        wt[L][0] = (unsigned short*)alloc((size_t)dims_in[L] * dims_h[L] * 2);
        wt[L][1] = (unsigned short*)alloc((size_t)dims_h[L] * dims_h[L] * 2);
    }
    (void)ws_size;

    // weight transpose-convert
    WT8 p;
    for (int L = 0; L < 4; ++L) {
        p.src[L * 2] = w[L][0];     p.dst[L * 2] = wt[L][0];
        p.K[L * 2] = dims_in[L];    p.N[L * 2] = dims_h[L];
        p.src[L * 2 + 1] = w[L][1]; p.dst[L * 2 + 1] = wt[L][1];
        p.K[L * 2 + 1] = dims_h[L]; p.N[L * 2 + 1] = dims_h[L];
    }
    wtconv_kernel<<<dim3(256, 8), 256, 0, stream>>>(p);

    // CSR build
    hipMemsetAsync(deg, 0, (size_t)N_NODES * 4, stream);
    hist_kernel<<<3125, 256, 0, stream>>>(dst, deg, N_EDGES);
    scan_reduce_kernel<<<SCAN_BLOCKS, 256, 0, stream>>>(deg, bsum, N_NODES);
    scan_bsum_kernel<<<1, 256, 0, stream>>>(bsum, SCAN_BLOCKS, rowptr, N_NODES);
    scan_apply_kernel<<<SCAN_BLOCKS, 256, 0, stream>>>(deg, bsum, rowptr, wptr, N_NODES);
    scatter_kernel<<<3125, 256, 0, stream>>>(src, dst, wptr, col, N_EDGES);

    const int gx = (N_NODES + 127) / 128;
    const int M = N_NODES;

    // ---- Layer 1 (commuted: GEMM1 256->128 reads fp32 x directly, agg@128+bias+relu, GEMM2) ----
    mfma_gemm2_kernel<8, true><<<dim3(gx, 1), 256, 0, stream>>>(
        x, wt[0][0], nullptr, bufA, M, 256, 128, 2, nullptr, nullptr, nullptr, nullptr);
    aggregate_bf16_kernel<16, true><<<(N_NODES + 15) / 16, 256, 0, stream>>>(
        bufA, rowptr, col, b[0][0], bufB, N_NODES);
    mfma_gemm2_kernel<8, false><<<dim3(gx, 1), 256, 0, stream>>>(
        bufB, wt[0][1], b[0][1], bufC, M, 128, 128, 1, bng[0], bnb[0], bnm[0], bnv[0]);

    // ---- Layer 2 (agg-first: agg@128, GEMM1 128->256 relu, GEMM2 256->256 BN) ----
    aggregate_bf16_kernel<16, false><<<(N_NODES + 15) / 16, 256, 0, stream>>>(
        bufC, rowptr, col, nullptr, bufA, N_NODES);
    mfma_gemm2_kernel<8, false><<<dim3(gx, 2), 256, 0, stream>>>(
        bufA, wt[1][0], b[1][0], bufB, M, 128, 256, 0, nullptr, nullptr, nullptr, nullptr);
    mfma_gemm2_kernel<8, false><<<dim3(gx, 2), 256, 0, stream>>>(
        bufB, wt[1][1], b[1][1], bufC, M, 256, 256, 1, bng[1], bnb[1], bnm[1], bnv[1]);

    // ---- Layer 3 (commuted: GEMM1 256->128, agg@128+bias+relu, GEMM2) ----
    mfma_gemm2_kernel<8, false><<<dim3(gx, 1), 256, 0, stream>>>(
        bufC, wt[2][0], nullptr, bufA, M, 256, 128, 2, nullptr, nullptr, nullptr, nullptr);
    aggregate_bf16_kernel<16, true><<<(N_NODES + 15) / 16, 256, 0, stream>>>(
        bufA, rowptr, col, b[2][0], bufB, N_NODES);
    mfma_gemm2_kernel<8, false><<<dim3(gx, 1), 256, 0, stream>>>(
        bufB, wt[2][1], b[2][1], bufC, M, 128, 128, 1, bng[2], bnb[2], bnm[2], bnv[2]);

    // ---- Layer 4 (commuted: GEMM1 128->64, agg@64+bias+relu, GEMM2 64->64 BN) ----
    mfma_gemm2_kernel<4, false><<<dim3(gx, 1), 256, 0, stream>>>(
        bufC, wt[3][0], nullptr, bufA, M, 128, 64, 2, nullptr, nullptr, nullptr, nullptr);
    aggregate_bf16_kernel<8, true><<<(N_NODES + 31) / 32, 256, 0, stream>>>(
        bufA, rowptr, col, b[3][0], bufB, N_NODES);
    mfma_gemm2_kernel<4, false><<<dim3(gx, 1), 256, 0, stream>>>(
        bufB, wt[3][1], b[3][1], bufC, M, 64, 64, 1, bng[3], bnb[3], bnm[3], bnv[3]);

    classifier_kernel<<<(N_NODES + 3) / 4, 256, 0, stream>>>(bufC, wc, bc, out, N_NODES);
}

// Round 6
// 549.075 us; speedup vs baseline: 2.2710x; 1.0406x over previous
//
#include <hip/hip_runtime.h>

#define N_NODES 50000
#define N_EDGES 800000
#define BN_EPS 1e-5f
#define SCAN_BLOCKS 196   // ceil(50000/256)
#define K_BUCK 196        // dst >> 8 buckets (256 nodes each)
#define PART_B 256        // partition blocks
#define CHUNK 3125        // N_EDGES / PART_B

typedef __attribute__((ext_vector_type(8))) short bshort8;
typedef __attribute__((ext_vector_type(4))) float f32x4;

__device__ inline float bf2f(unsigned int u16) {
    return __uint_as_float(u16 << 16);
}
__device__ inline unsigned short f2bf(float f) {
    unsigned int u = __float_as_uint(f);
    u = (u + 0x7FFFu + ((u >> 16) & 1u)) >> 16;
    return (unsigned short)u;
}

// ---------------- CSR build ----------------

__global__ void hist_kernel(const int* __restrict__ dst, int* __restrict__ deg, int e) {
    int i = blockIdx.x * blockDim.x + threadIdx.x;
    int stride = gridDim.x * blockDim.x;
    for (; i < e; i += stride) atomicAdd(&deg[dst[i]], 1);
}

__device__ inline int block_exscan256(int v, int tid, int* total) {
    int lane = tid & 63;
    int wave = tid >> 6;
    int incl = v;
#pragma unroll
    for (int off = 1; off < 64; off <<= 1) {
        int t = __shfl_up(incl, off, 64);
        if (lane >= off) incl += t;
    }
    __shared__ int wsum[4];
    if (lane == 63) wsum[wave] = incl;
    __syncthreads();
    int w0 = wsum[0], w1 = wsum[1], w2 = wsum[2], w3 = wsum[3];
    __syncthreads();
    int wofs = (wave > 0 ? w0 : 0) + (wave > 1 ? w1 : 0) + (wave > 2 ? w2 : 0);
    *total = w0 + w1 + w2 + w3;
    return wofs + incl - v;
}

__global__ __launch_bounds__(256) void scan_reduce_kernel(const int* __restrict__ in,
                                                          int* __restrict__ bsum, int n) {
    int tid = threadIdx.x;
    int i = blockIdx.x * 256 + tid;
    int v = (i < n) ? in[i] : 0;
    int lane = tid & 63;
    int wave = tid >> 6;
#pragma unroll
    for (int off = 32; off > 0; off >>= 1) v += __shfl_down(v, off, 64);
    __shared__ int wsum[4];
    if (lane == 0) wsum[wave] = v;
    __syncthreads();
    if (tid == 0) bsum[blockIdx.x] = wsum[0] + wsum[1] + wsum[2] + wsum[3];
}

__global__ __launch_bounds__(256) void scan_bsum_kernel(int* __restrict__ bsum, int B,
                                                        int* __restrict__ totout) {
    int tid = threadIdx.x;
    int v = (tid < B) ? bsum[tid] : 0;
    int total;
    int excl = block_exscan256(v, tid, &total);
    if (tid < B) bsum[tid] = excl;
    if (tid == 0) *totout = total;
}

// out[i] = bsum[blk] + exclusive_prefix(in[i]); in-place safe (in==out ok)
__global__ __launch_bounds__(256) void scan_apply_kernel(const int* __restrict__ in,
                                                         const int* __restrict__ bsum,
                                                         int* __restrict__ out, int n) {
    int tid = threadIdx.x;
    int i = blockIdx.x * 256 + tid;
    int v = (i < n) ? in[i] : 0;
    int total;
    int excl = block_exscan256(v, tid, &total);
    if (i < n) out[i] = bsum[blockIdx.x] + excl;
}

// ---- bucketed scatter (replaces random single-pass scatter) ----

// count[(bucket, block)] with bucket-major layout for the scan
__global__ __launch_bounds__(256) void bucket_count_kernel(const int* __restrict__ dst,
                                                           int* __restrict__ cnt) {
    __shared__ int lcnt[K_BUCK];
    int tid = threadIdx.x;
    for (int i = tid; i < K_BUCK; i += 256) lcnt[i] = 0;
    __syncthreads();
    int start = blockIdx.x * CHUNK;
    for (int it = tid; it < CHUNK; it += 256)
        atomicAdd(&lcnt[dst[start + it] >> 8], 1);
    __syncthreads();
    for (int i = tid; i < K_BUCK; i += 256) cnt[i * PART_B + blockIdx.x] = lcnt[i];
}

// partition edges into bucket-contiguous P[] = (dst, src)
__global__ __launch_bounds__(256) void partition_kernel(const int* __restrict__ src,
                                                        const int* __restrict__ dst,
                                                        const int* __restrict__ base,
                                                        uint2* __restrict__ P) {
    __shared__ int lofs[K_BUCK];
    int tid = threadIdx.x;
    for (int i = tid; i < K_BUCK; i += 256) lofs[i] = base[i * PART_B + blockIdx.x];
    __syncthreads();
    int start = blockIdx.x * CHUNK;
    for (int it = tid; it < CHUNK; it += 256) {
        int e = start + it;
        int d = dst[e], s = src[e];
        int p = atomicAdd(&lofs[d >> 8], 1);
        P[p] = make_uint2((unsigned)d, (unsigned)s);
    }
}

// one block per bucket: LDS write-cursors, col writes confined to a 16KB window
__global__ __launch_bounds__(256) void fine_scatter_kernel(const uint2* __restrict__ P,
                                                           const int* __restrict__ base,
                                                           const int* __restrict__ rowptr,
                                                           int* __restrict__ col) {
    __shared__ int wloc[256];
    int b = blockIdx.x;
    int tid = threadIdx.x;
    int nbase = b << 8;
    int nn = min(256, N_NODES - nbase);
    if (tid < nn) wloc[tid] = rowptr[nbase + tid];
    __syncthreads();
    int start = base[b * PART_B];
    int end = (b + 1 < K_BUCK) ? base[(b + 1) * PART_B] : N_EDGES;
    for (int e = start + tid; e < end; e += 256) {
        uint2 pr = P[e];
        int rank = atomicAdd(&wloc[pr.x - nbase], 1);
        col[rank] = (int)pr.y;
    }
}

// ---------------- conversions ----------------

struct WT8 {
    const float* src[8];
    unsigned short* dst[8];
    int K[8];
    int N[8];
};

// W[K][N] fp32 -> Wt[N][K] bf16 (N,K are powers of two)
__global__ __launch_bounds__(256) void wtconv_kernel(WT8 p) {
    int wi = blockIdx.y;
    int K = p.K[wi], N = p.N[wi];
    int idx = blockIdx.x * 256 + threadIdx.x;
    if (idx >= K * N) return;
    int logn = 31 - __clz(N);
    int n = idx & (N - 1);
    int k = idx >> logn;
    p.dst[wi][(size_t)n * K + k] = f2bf(p.src[wi][idx]);
}

// ---------------- aggregation (bf16): z[i] = h[i] + sum_{j in N(i)} h[j] ----------------

__device__ inline void acc8(uint4 v, float* a) {
    a[0] += bf2f(v.x & 0xFFFFu); a[1] += __uint_as_float(v.x & 0xFFFF0000u);
    a[2] += bf2f(v.y & 0xFFFFu); a[3] += __uint_as_float(v.y & 0xFFFF0000u);
    a[4] += bf2f(v.z & 0xFFFFu); a[5] += __uint_as_float(v.z & 0xFFFF0000u);
    a[6] += bf2f(v.w & 0xFFFFu); a[7] += __uint_as_float(v.w & 0xFFFF0000u);
}

template <int LPN, bool RELU>
__global__ __launch_bounds__(256) void aggregate_bf16_kernel(
    const unsigned short* __restrict__ h, const int* __restrict__ rowptr,
    const int* __restrict__ col, const float* __restrict__ bias,
    unsigned short* __restrict__ z, int n) {
    const int gpb = 256 / LPN;
    int gid = threadIdx.x / LPN;
    int l = threadIdx.x % LPN;
    int node = blockIdx.x * gpb + gid;
    if (node >= n) return;
    const uint4* hv = (const uint4*)h;
    float a[8] = {};
    acc8(hv[(size_t)node * LPN + l], a);  // self
    int s = rowptr[node], epos = rowptr[node + 1];
    for (int e = s; e < epos; ++e) {
        int j = col[e];
        acc8(hv[(size_t)j * LPN + l], a);
    }
    if (RELU) {
        float4 b0 = *(const float4*)(bias + l * 8);
        float4 b1 = *(const float4*)(bias + l * 8 + 4);
        a[0] = fmaxf(a[0] + b0.x, 0.f); a[1] = fmaxf(a[1] + b0.y, 0.f);
        a[2] = fmaxf(a[2] + b0.z, 0.f); a[3] = fmaxf(a[3] + b0.w, 0.f);
        a[4] = fmaxf(a[4] + b1.x, 0.f); a[5] = fmaxf(a[5] + b1.y, 0.f);
        a[6] = fmaxf(a[6] + b1.z, 0.f); a[7] = fmaxf(a[7] + b1.w, 0.f);
    }
    uint4 o;
    o.x = (unsigned int)f2bf(a[0]) | ((unsigned int)f2bf(a[1]) << 16);
    o.y = (unsigned int)f2bf(a[2]) | ((unsigned int)f2bf(a[3]) << 16);
    o.z = (unsigned int)f2bf(a[4]) | ((unsigned int)f2bf(a[5]) << 16);
    o.w = (unsigned int)f2bf(a[6]) | ((unsigned int)f2bf(a[7]) << 16);
    ((uint4*)z)[(size_t)node * LPN + l] = o;
}

// ---------------- bf16 MFMA GEMM v2 ----------------
// C = epilogue(A @ Wt^T). A: M x K (bf16, or fp32 if F32A). Wt: Nn x K bf16.
// BM=128, BK=64, BN=NT*16. Software-pipelined; A/B staged in LDS; epilogue
// through LDS -> coalesced 16B stores.
// mode 0: relu(acc+b); 1: relu((acc+b-mu)*g*rsqrt(var+eps)+be); 2: raw acc

template <int NT, bool F32A>
__global__ __launch_bounds__(256) void mfma_gemm2_kernel(
    const void* __restrict__ Ain, const unsigned short* __restrict__ Wt,
    const float* __restrict__ bias, unsigned short* __restrict__ C,
    int M, int K, int Nn, int mode,
    const float* __restrict__ g, const float* __restrict__ be,
    const float* __restrict__ mu, const float* __restrict__ var) {
    constexpr int BM = 128, BK = 64;
    constexpr int BN = NT * 16;
    constexpr int LDA = BK + 8;
    constexpr int LDB = BK + 8;
    constexpr int LDE = BN + 8;
    constexpr int NB_LD = (BN * BK / 8) / 256;
    __shared__ __align__(16) unsigned short smem[BM * LDA + BN * LDB];
    unsigned short* As = smem;
    unsigned short* Bs = smem + BM * LDA;
    unsigned short* Ep = smem;

    const int tid = threadIdx.x;
    const int wv = tid >> 6;
    const int ln = tid & 63;
    const int l15 = ln & 15;
    const int quad = ln >> 4;
    const int row0 = blockIdx.x * BM;
    const int col0 = blockIdx.y * BN;

    const unsigned short* A16 = (const unsigned short*)Ain;
    const float* A32 = (const float*)Ain;

    uint4 Ar[4], Br[NB_LD];

    auto loadA = [&](int k0) {
#pragma unroll
        for (int u = 0; u < 4; ++u) {
            int idx2 = tid + 256 * u;
            int r = idx2 >> 3, cg = (idx2 & 7) * 8;
            int gr = row0 + r;
            if (gr >= M) gr = M - 1;
            if (F32A) {
                float4 f0 = *(const float4*)(A32 + (size_t)gr * K + k0 + cg);
                float4 f1 = *(const float4*)(A32 + (size_t)gr * K + k0 + cg + 4);
                uint4 o;
                o.x = (unsigned)f2bf(f0.x) | ((unsigned)f2bf(f0.y) << 16);
                o.y = (unsigned)f2bf(f0.z) | ((unsigned)f2bf(f0.w) << 16);
                o.z = (unsigned)f2bf(f1.x) | ((unsigned)f2bf(f1.y) << 16);
                o.w = (unsigned)f2bf(f1.z) | ((unsigned)f2bf(f1.w) << 16);
                Ar[u] = o;
            } else {
                Ar[u] = *(const uint4*)(A16 + (size_t)gr * K + k0 + cg);
            }
        }
    };
    auto loadB = [&](int k0) {
#pragma unroll
        for (int u = 0; u < NB_LD; ++u) {
            int idx2 = tid + 256 * u;
            int r = idx2 >> 3, cg = (idx2 & 7) * 8;
            Br[u] = *(const uint4*)(Wt + (size_t)(col0 + r) * K + k0 + cg);
        }
    };
    auto stage = [&]() {
#pragma unroll
        for (int u = 0; u < 4; ++u) {
            int idx2 = tid + 256 * u;
            int r = idx2 >> 3, cg = (idx2 & 7) * 8;
            *(uint4*)(&As[r * LDA + cg]) = Ar[u];
        }
#pragma unroll
        for (int u = 0; u < NB_LD; ++u) {
            int idx2 = tid + 256 * u;
            int r = idx2 >> 3, cg = (idx2 & 7) * 8;
            *(uint4*)(&Bs[r * LDB + cg]) = Br[u];
        }
    };

    f32x4 acc[2][NT] = {};
    const int KT = K >> 6;
    loadA(0);
    loadB(0);
    for (int kt = 0; kt < KT; ++kt) {
        if (kt > 0) __syncthreads();
        stage();
        __syncthreads();
        if (kt + 1 < KT) {
            loadA((kt + 1) * 64);
            loadB((kt + 1) * 64);
        }
#pragma unroll
        for (int kh = 0; kh < 2; ++kh) {
            bshort8 af[2];
#pragma unroll
            for (int mt = 0; mt < 2; ++mt)
                af[mt] = *(const bshort8*)(&As[(wv * 32 + mt * 16 + l15) * LDA + kh * 32 + quad * 8]);
#pragma unroll
            for (int nt = 0; nt < NT; ++nt) {
                bshort8 bf = *(const bshort8*)(&Bs[(nt * 16 + l15) * LDB + kh * 32 + quad * 8]);
                acc[0][nt] = __builtin_amdgcn_mfma_f32_16x16x32_bf16(af[0], bf, acc[0][nt], 0, 0, 0);
                acc[1][nt] = __builtin_amdgcn_mfma_f32_16x16x32_bf16(af[1], bf, acc[1][nt], 0, 0, 0);
            }
        }
    }

    __syncthreads();
#pragma unroll
    for (int nt = 0; nt < NT; ++nt) {
        int c = col0 + nt * 16 + l15;
        float s = 1.f, sh = 0.f;
        if (mode == 0) {
            sh = bias[c];
        } else if (mode == 1) {
            float t = g[c] * rsqrtf(var[c] + BN_EPS);
            s = t;
            sh = be[c] - mu[c] * t + bias[c] * t;
        }
#pragma unroll
        for (int mt = 0; mt < 2; ++mt) {
            int rl = wv * 32 + mt * 16 + quad * 4;
#pragma unroll
            for (int r = 0; r < 4; ++r) {
                float v = acc[mt][nt][r] * s + sh;
                if (mode != 2) v = fmaxf(v, 0.f);
                Ep[(rl + r) * LDE + nt * 16 + l15] = f2bf(v);
            }
        }
    }
    __syncthreads();
    constexpr int CGR = BN / 8;
    constexpr int NU = BM * CGR / 256;
#pragma unroll
    for (int u = 0; u < NU; ++u) {
        int idx2 = tid + 256 * u;
        int r = idx2 / CGR, cg = (idx2 % CGR) * 8;
        int grow = row0 + r;
        if (grow < M)
            *(uint4*)(C + (size_t)grow * Nn + col0 + cg) = *(const uint4*)(&Ep[r * LDE + cg]);
    }
}

// ---------------- classifier: out = h @ wc + bc, K=64, Nout=2, fp32 out ----------------

__global__ __launch_bounds__(256) void classifier_kernel(
    const unsigned short* __restrict__ h, const float* __restrict__ wc,
    const float* __restrict__ bc, float* __restrict__ out, int n) {
    int wave = threadIdx.x >> 6;
    int lane = threadIdx.x & 63;
    int row = blockIdx.x * 4 + wave;
    if (row >= n) return;
    float v = bf2f(h[(size_t)row * 64 + lane]);
    float s0 = v * wc[lane * 2 + 0];
    float s1 = v * wc[lane * 2 + 1];
#pragma unroll
    for (int off = 32; off > 0; off >>= 1) {
        s0 += __shfl_down(s0, off, 64);
        s1 += __shfl_down(s1, off, 64);
    }
    if (lane == 0) {
        out[(size_t)row * 2 + 0] = s0 + bc[0];
        out[(size_t)row * 2 + 1] = s1 + bc[1];
    }
}

// ---------------- launch ----------------

extern "C" void kernel_launch(void* const* d_in, const int* in_sizes, int n_in,
                              void* d_out, int out_size, void* d_ws, size_t ws_size,
                              hipStream_t stream) {
    const float* x = (const float*)d_in[0];
    const int* ei = (const int*)d_in[1];
    const int* src = ei;
    const int* dst = ei + N_EDGES;
    const float* w[4][2];
    const float* b[4][2];
    const float* bng[4];
    const float* bnb[4];
    const float* bnm[4];
    const float* bnv[4];
    int idx = 2;
    for (int i = 0; i < 4; ++i) {
        w[i][0] = (const float*)d_in[idx++];
        b[i][0] = (const float*)d_in[idx++];
        w[i][1] = (const float*)d_in[idx++];
        b[i][1] = (const float*)d_in[idx++];
        bng[i] = (const float*)d_in[idx++];
        bnb[i] = (const float*)d_in[idx++];
        bnm[i] = (const float*)d_in[idx++];
        bnv[i] = (const float*)d_in[idx++];
    }
    const float* wc = (const float*)d_in[idx++];
    const float* bc = (const float*)d_in[idx++];
    float* out = (float*)d_out;

    char* ws = (char*)d_ws;
    size_t off = 0;
    auto alloc = [&](size_t bytes) {
        char* p = ws + off;
        off = (off + bytes + 255) & ~(size_t)255;
        return p;
    };
    int* deg = (int*)alloc((size_t)N_NODES * 4);
    int* rowptr = (int*)alloc((size_t)(N_NODES + 1) * 4);
    int* bsum = (int*)alloc((size_t)SCAN_BLOCKS * 4);
    int* cnt = (int*)alloc((size_t)K_BUCK * PART_B * 4);
    int* bsum2 = (int*)alloc((size_t)K_BUCK * 4);
    int* scratch = (int*)alloc(256);
    int* col = (int*)alloc((size_t)N_EDGES * 4);
    uint2* P = (uint2*)alloc((size_t)N_EDGES * 8);
    unsigned short* bufA = (unsigned short*)alloc((size_t)N_NODES * 256 * 2);
    unsigned short* bufB = (unsigned short*)alloc((size_t)N_NODES * 256 * 2);
    unsigned short* bufC = (unsigned short*)alloc((size_t)N_NODES * 256 * 2);
    const int dims_in[4] = {256, 128, 256, 128};
    const int dims_h[4] = {128, 256, 128, 64};
    unsigned short* wt[4][2];
    for (int L = 0; L < 4; ++L) {
        wt[L][0] = (unsigned short*)alloc((size_t)dims_in[L] * dims_h[L] * 2);
        wt[L][1] = (unsigned short*)alloc((size_t)dims_h[L] * dims_h[L] * 2);
    }
    (void)ws_size;

    // weight transpose-convert
    WT8 p;
    for (int L = 0; L < 4; ++L) {
        p.src[L * 2] = w[L][0];     p.dst[L * 2] = wt[L][0];
        p.K[L * 2] = dims_in[L];    p.N[L * 2] = dims_h[L];
        p.src[L * 2 + 1] = w[L][1]; p.dst[L * 2 + 1] = wt[L][1];
        p.K[L * 2 + 1] = dims_h[L]; p.N[L * 2 + 1] = dims_h[L];
    }
    wtconv_kernel<<<dim3(256, 8), 256, 0, stream>>>(p);

    // ---- CSR build ----
    // rowptr: hist + hierarchical exclusive scan
    hipMemsetAsync(deg, 0, (size_t)N_NODES * 4, stream);
    hist_kernel<<<3125, 256, 0, stream>>>(dst, deg, N_EDGES);
    scan_reduce_kernel<<<SCAN_BLOCKS, 256, 0, stream>>>(deg, bsum, N_NODES);
    scan_bsum_kernel<<<1, 256, 0, stream>>>(bsum, SCAN_BLOCKS, rowptr + N_NODES);
    scan_apply_kernel<<<SCAN_BLOCKS, 256, 0, stream>>>(deg, bsum, rowptr, N_NODES);
    // bucketed scatter: count -> scan -> partition -> fine (LDS cursors)
    bucket_count_kernel<<<PART_B, 256, 0, stream>>>(dst, cnt);
    scan_reduce_kernel<<<K_BUCK, 256, 0, stream>>>(cnt, bsum2, K_BUCK * PART_B);
    scan_bsum_kernel<<<1, 256, 0, stream>>>(bsum2, K_BUCK, scratch);
    scan_apply_kernel<<<K_BUCK, 256, 0, stream>>>(cnt, bsum2, cnt, K_BUCK * PART_B);
    partition_kernel<<<PART_B, 256, 0, stream>>>(src, dst, cnt, P);
    fine_scatter_kernel<<<K_BUCK, 256, 0, stream>>>(P, cnt, rowptr, col);

    const int gx = (N_NODES + 127) / 128;
    const int M = N_NODES;

    // ---- Layer 1 (commuted: GEMM1 256->128 reads fp32 x directly, agg@128+bias+relu, GEMM2) ----
    mfma_gemm2_kernel<8, true><<<dim3(gx, 1), 256, 0, stream>>>(
        x, wt[0][0], nullptr, bufA, M, 256, 128, 2, nullptr, nullptr, nullptr, nullptr);
    aggregate_bf16_kernel<16, true><<<(N_NODES + 15) / 16, 256, 0, stream>>>(
        bufA, rowptr, col, b[0][0], bufB, N_NODES);
    mfma_gemm2_kernel<8, false><<<dim3(gx, 1), 256, 0, stream>>>(
        bufB, wt[0][1], b[0][1], bufC, M, 128, 128, 1, bng[0], bnb[0], bnm[0], bnv[0]);

    // ---- Layer 2 (agg-first: agg@128, GEMM1 128->256 relu, GEMM2 256->256 BN) ----
    aggregate_bf16_kernel<16, false><<<(N_NODES + 15) / 16, 256, 0, stream>>>(
        bufC, rowptr, col, nullptr, bufA, N_NODES);
    mfma_gemm2_kernel<8, false><<<dim3(gx, 2), 256, 0, stream>>>(
        bufA, wt[1][0], b[1][0], bufB, M, 128, 256, 0, nullptr, nullptr, nullptr, nullptr);
    mfma_gemm2_kernel<8, false><<<dim3(gx, 2), 256, 0, stream>>>(
        bufB, wt[1][1], b[1][1], bufC, M, 256, 256, 1, bng[1], bnb[1], bnm[1], bnv[1]);

    // ---- Layer 3 (commuted: GEMM1 256->128, agg@128+bias+relu, GEMM2) ----
    mfma_gemm2_kernel<8, false><<<dim3(gx, 1), 256, 0, stream>>>(
        bufC, wt[2][0], nullptr, bufA, M, 256, 128, 2, nullptr, nullptr, nullptr, nullptr);
    aggregate_bf16_kernel<16, true><<<(N_NODES + 15) / 16, 256, 0, stream>>>(
        bufA, rowptr, col, b[2][0], bufB, N_NODES);
    mfma_gemm2_kernel<8, false><<<dim3(gx, 1), 256, 0, stream>>>(
        bufB, wt[2][1], b[2][1], bufC, M, 128, 128, 1, bng[2], bnb[2], bnm[2], bnv[2]);

    // ---- Layer 4 (commuted: GEMM1 128->64, agg@64+bias+relu, GEMM2 64->64 BN) ----
    mfma_gemm2_kernel<4, false><<<dim3(gx, 1), 256, 0, stream>>>(
        bufC, wt[3][0], nullptr, bufA, M, 128, 64, 2, nullptr, nullptr, nullptr, nullptr);
    aggregate_bf16_kernel<8, true><<<(N_NODES + 31) / 32, 256, 0, stream>>>(
        bufA, rowptr, col, b[3][0], bufB, N_NODES);
    mfma_gemm2_kernel<4, false><<<dim3(gx, 1), 256, 0, stream>>>(
        bufB, wt[3][1], b[3][1], bufC, M, 64, 64, 1, bng[3], bnb[3], bnm[3], bnv[3]);

    classifier_kernel<<<(N_NODES + 3) / 4, 256, 0, stream>>>(bufC, wc, bc, out, N_NODES);
}